// Round 14
// baseline (535.476 us; speedup 1.0000x reference)
//
#include <hip/hip_runtime.h>
#include <hip/hip_bf16.h>
#include <math.h>

// Problem constants (from reference)
#define BGRAPH 8192
#define NPG 32
#define EPG 64
#define NNODE (BGRAPH * NPG)   // 262144
#define NEDGE (BGRAPH * EPG)   // 524288
#define CELLD 908
#define BN_EPS 1e-5f
#define ABF_STR 1024           // bf16 cell row stride (zero-padded, mult of 128)
#define C1_STR 640             // bf16 c1 row stride (516 padded to mult of 128)

typedef __attribute__((ext_vector_type(8))) short bf16x8;   // 8 bf16 = 4 VGPRs
typedef __attribute__((ext_vector_type(4))) float f32x4;
typedef __attribute__((ext_vector_type(4))) unsigned short us4;
typedef __attribute__((ext_vector_type(8))) unsigned short us8;

__device__ __forceinline__ unsigned short f2bf(float f)
{
    unsigned int u = __float_as_uint(f);
    u = (u + 0x7FFFu + ((u >> 16) & 1u)) >> 16;   // RNE
    return (unsigned short)u;
}

__device__ __forceinline__ bf16x8 quant8(const float v[8])
{
    union { bf16x8 b; unsigned short u[8]; } fr;
    #pragma unroll
    for (int j = 0; j < 8; ++j) fr.u[j] = f2bf(v[j]);
    return fr.b;
}

__device__ __forceinline__ void bf2f8(bf16x8 b, float v[8])
{
    union { bf16x8 bb; unsigned short u[8]; } x; x.bb = b;
    #pragma unroll
    for (int j = 0; j < 8; ++j) v[j] = __uint_as_float((unsigned)x.u[j] << 16);
}

// in_mode: 0=raw, 1=relu((x-m)*iv), 2=elu((x-m)*iv), 3=(relu(x)-m)*iv
__device__ __forceinline__ float apply_in(float v, int mode, float mn, float iv)
{
    if (mode == 1)      { v = (v - mn) * iv; v = fmaxf(v, 0.f); }
    else if (mode == 2) { v = (v - mn) * iv; v = (v > 0.f) ? v : expm1f(v); }
    else if (mode == 3) { v = fmaxf(v, 0.f); v = (v - mn) * iv; }
    return v;
}

// ===========================================================================
// Device bodies (shared-memory passed in so fused kernels can union them)
// ===========================================================================
struct TransArgs {
    const float* w[11];
    unsigned short* wt[11];
    int K[11], N[11], ntN[11];
    int off[12];
};
struct TransSmem { float t[64][65]; };

__device__ void dev_transpose(TransSmem* sm, int b, const TransArgs& a)
{
    int tid = threadIdx.x;
    int s = 0;
    while (s < 10 && b >= a.off[s + 1]) ++s;
    int t0 = b - a.off[s];
    int K = a.K[s], N = a.N[s], ntn = a.ntN[s];
    int kt = t0 / ntn, nt = t0 - kt * ntn;
    int k0 = kt * 64, n0 = nt * 64;
    const float* w = a.w[s];
    unsigned short* wt = a.wt[s];
    int c = tid & 63, rg = tid >> 6;
    #pragma unroll
    for (int i = 0; i < 16; ++i) {
        int rr = rg * 16 + i;
        int k = k0 + rr, n = n0 + c;
        sm->t[c][rr] = (k < K && n < N) ? w[(size_t)k * N + n] : 0.f;
    }
    __syncthreads();
    #pragma unroll
    for (int i = 0; i < 16; ++i) {
        int rr = rg * 16 + i;
        int n = n0 + rr, k = k0 + c;
        if (n < N && k < K) wt[(size_t)n * K + k] = f2bf(sm->t[rr][c]);
    }
}

struct SetupArgs {
    float* zb; int zTotal; int zBlocks;
    const int* src; const int* dst; int* row_start; int* col_idx;
};
struct SetupSmem { int cnt[4][32]; int fill[4][32]; int rsl[4][33]; };

__device__ void dev_setup(SetupSmem* sm, int b, const SetupArgs& a)
{
    int tid = threadIdx.x;
    if (b < a.zBlocks) {
        int i = b * 256 + tid;
        if (i < a.zTotal) a.zb[i] = 0.f;
        return;
    }
    b -= a.zBlocks;
    int gl = tid >> 6, e = tid & 63;
    int g = b * 4 + gl;
    if (e < 32) { sm->cnt[gl][e] = 0; sm->fill[gl][e] = 0; }
    __syncthreads();
    int s = a.src[g * EPG + e] - g * NPG;
    int d = a.dst[g * EPG + e] - g * NPG;
    atomicAdd(&sm->cnt[gl][d], 1);
    __syncthreads();
    if (e == 0) {
        int acc = 0;
        for (int i = 0; i < 32; ++i) { sm->rsl[gl][i] = acc; acc += sm->cnt[gl][i]; }
        sm->rsl[gl][32] = acc;
    }
    __syncthreads();
    int pos = sm->rsl[gl][d] + atomicAdd(&sm->fill[gl][d], 1);
    a.col_idx[g * EPG + pos] = s;
    if (e < 33) a.row_start[g * 33 + e] = sm->rsl[gl][e];
}

__device__ void dev_quant_cell(int bid, const float* __restrict__ cell,
                               unsigned short* __restrict__ abf)
{
    int i = bid * 256 + threadIdx.x;
    int row = i / (ABF_STR / 4), c4 = i - row * (ABF_STR / 4);
    int k = c4 * 4;
    us4 w = (us4){0, 0, 0, 0};
    if (k < CELLD) {
        float4 f = *(const float4*)&cell[(size_t)row * CELLD + k];
        w = (us4){ f2bf(f.x), f2bf(f.y), f2bf(f.z), f2bf(f.w) };
    }
    *(us4*)&abf[(size_t)row * ABF_STR + k] = w;
}

__device__ void dev_quant_c1(int bid, const float* __restrict__ c1,
                             const float* __restrict__ stats, float inv_sM,
                             unsigned short* __restrict__ out)
{
    int i = bid * 256 + threadIdx.x;
    int row = i / (C1_STR / 4), c4 = i - row * (C1_STR / 4);
    int k = c4 * 4;
    us4 w = (us4){0, 0, 0, 0};
    if (k < 516) {
        float4 f = *(const float4*)&c1[(size_t)row * 516 + k];
        float v[4] = {f.x, f.y, f.z, f.w};
        #pragma unroll
        for (int j = 0; j < 4; ++j) {
            float s = stats[k + j], ss = stats[516 + k + j];
            float mn = s * inv_sM;
            float iv = rsqrtf(ss * inv_sM - mn * mn + BN_EPS);
            v[j] = fmaxf((v[j] - mn) * iv, 0.f);
        }
        w = (us4){ f2bf(v[0]), f2bf(v[1]), f2bf(v[2]), f2bf(v[3]) };
    }
    *(us4*)&out[(size_t)row * C1_STR + k] = w;
}

__device__ void dev_reduce(int bid, const float* __restrict__ part, int nrows,
                           int nt, float* __restrict__ out)
{
    int c = threadIdx.x;
    int per = nrows >> 6;
    int r0 = bid * per;
    bool isq = (c >= 128);
    int cc = isq ? c - 128 : c;
    if (cc >= nt) return;
    float s = 0.f;
    for (int r = 0; r < per; ++r) s += part[(size_t)(r0 + r) * 256 + c];
    unsafeAtomicAdd(&out[(isq ? nt : 0) + cc], s);
}

// ---------------------------------------------------------------------------
// gin_s1 body (LDS slimmed: x tile is fp32 32x16 per wave -- the old bf16
// h[4*32*136] allocation was a fossil costing 27 KB of dead LDS)
// ---------------------------------------------------------------------------
struct S1Smem {
    float xw[4][32 * 16];
    unsigned char ubuf[4096];
    int rs[4][36];
    int ci[4][64];
};

__device__ void dev_gin_s1(S1Smem* sm, int bid,
                           const float* __restrict__ drug_x,
                           const int* __restrict__ row_start,
                           const int* __restrict__ col_idx,
                           const unsigned short* __restrict__ W11,
                           const float* __restrict__ b11,
                           unsigned short* uout, float* __restrict__ part)
{
    unsigned short* w11l = (unsigned short*)sm->ubuf;
    float* red = (float*)sm->ubuf;

    int tid  = threadIdx.x;
    int wave = tid >> 6;
    int lane = tid & 63;
    int quad = lane >> 4;
    int l16  = lane & 15;
    int g0   = bid * 4;
    float* xw = sm->xw[wave];

    for (int i = tid; i < 128 * 16; i += 256) {
        int n = i >> 4, k = i & 15;
        w11l[i] = (k < 9) ? W11[n * 9 + k] : (unsigned short)0;
    }
    if (tid < 132) {
        int gl = tid / 33, idx = tid - gl * 33;
        sm->rs[gl][idx] = row_start[(g0 + gl) * 33 + idx];
    }
    {
        int gl = tid >> 6, e = tid & 63;
        sm->ci[gl][e] = col_idx[(g0 + gl) * EPG + e];
    }
    {
        const float* xg = drug_x + (size_t)(g0 + wave) * 32 * 9;
        for (int i = lane; i < 32 * 16; i += 64) {
            int rr = i >> 4, c = i & 15;
            xw[i] = (c < 9) ? xg[rr * 9 + c] : 0.f;
        }
    }
    __syncthreads();

    f32x4 acc[2][8];
    #pragma unroll
    for (int i = 0; i < 2; ++i)
        #pragma unroll
        for (int j = 0; j < 8; ++j)
            acc[i][j] = (f32x4){0.f, 0.f, 0.f, 0.f};

    {
        bf16x8 af[2];
        #pragma unroll
        for (int mt = 0; mt < 2; ++mt) {
            int rowl = mt * 16 + l16;
            float v[8] = {0, 0, 0, 0, 0, 0, 0, 0};
            if (quad < 2) {
                float4 lo = *(const float4*)&xw[rowl * 16 + quad * 8];
                float4 hi = *(const float4*)&xw[rowl * 16 + quad * 8 + 4];
                v[0] = lo.x; v[1] = lo.y; v[2] = lo.z; v[3] = lo.w;
                v[4] = hi.x; v[5] = hi.y; v[6] = hi.z; v[7] = hi.w;
                int e0 = sm->rs[wave][rowl], e1 = sm->rs[wave][rowl + 1];
                for (int e = e0; e < e1; ++e) {
                    int sr = sm->ci[wave][e];
                    float4 l2 = *(const float4*)&xw[sr * 16 + quad * 8];
                    float4 h2 = *(const float4*)&xw[sr * 16 + quad * 8 + 4];
                    v[0] += l2.x; v[1] += l2.y; v[2] += l2.z; v[3] += l2.w;
                    v[4] += h2.x; v[5] += h2.y; v[6] += h2.z; v[7] += h2.w;
                }
            }
            af[mt] = quant8(v);
        }
        #pragma unroll
        for (int nt = 0; nt < 8; ++nt) {
            bf16x8 b;
            if (quad < 2) b = *(const bf16x8*)(const void*)&w11l[(nt * 16 + l16) * 16 + quad * 8];
            else { float z[8] = {0,0,0,0,0,0,0,0}; b = quant8(z); }
            acc[0][nt] = __builtin_amdgcn_mfma_f32_16x16x32_bf16(af[0], b, acc[0][nt], 0, 0, 0);
            acc[1][nt] = __builtin_amdgcn_mfma_f32_16x16x32_bf16(af[1], b, acc[1][nt], 0, 0, 0);
        }
    }

    float ls[8], lq[8];
    unsigned short* ub = uout + (size_t)(g0 + wave) * 32 * 128;
    #pragma unroll
    for (int nt = 0; nt < 8; ++nt) {
        int col = nt * 16 + l16;
        float bv = b11[col];
        float s0 = 0.f, q0 = 0.f;
        #pragma unroll
        for (int mt = 0; mt < 2; ++mt) {
            int rb = mt * 16 + quad * 4;
            #pragma unroll
            for (int r = 0; r < 4; ++r) {
                float u = acc[mt][nt][r] + bv;
                ub[(size_t)(rb + r) * 128 + col] = f2bf(u);
                s0 += u; q0 += u * u;
            }
        }
        ls[nt] = s0; lq[nt] = q0;
    }
    __syncthreads();
    #pragma unroll
    for (int nt = 0; nt < 8; ++nt) {
        float s = ls[nt], q = lq[nt];
        s += __shfl_xor(s, 16); q += __shfl_xor(q, 16);
        s += __shfl_xor(s, 32); q += __shfl_xor(q, 32);
        if (quad == 0) {
            int col = nt * 16 + l16;
            red[(wave * 2 + 0) * 128 + col] = s;
            red[(wave * 2 + 1) * 128 + col] = q;
        }
    }
    __syncthreads();
    if (tid < 128) {
        float s = red[0 * 128 + tid] + red[2 * 128 + tid] + red[4 * 128 + tid] + red[6 * 128 + tid];
        float q = red[1 * 128 + tid] + red[3 * 128 + tid] + red[5 * 128 + tid] + red[7 * 128 + tid];
        part[(size_t)bid * 256 + tid] = s;
        part[(size_t)bid * 256 + 128 + tid] = q;
    }
}

// ---------------------------------------------------------------------------
// gin_s3f body (fused GEMM+aggregation, W LDS tile, zt overlay)
// ---------------------------------------------------------------------------
struct S3fSmem {
    unsigned short wsl[128 * 136];
    float pmv[256];
    int rs[2][33];
    int ci[2][64];
};

__device__ void dev_gin_s3f(S3fSmem* sm, int bid,
                            const unsigned short* __restrict__ uin,
                            const int* __restrict__ row_start,
                            const int* __restrict__ col_idx,
                            const unsigned short* __restrict__ Wt,
                            const float* __restrict__ bias,
                            const float* __restrict__ in_stats, float inv_sM,
                            unsigned short* __restrict__ uout,
                            float* __restrict__ part)
{
    float* zt = (float*)sm->wsl;   // 64*132 floats overlay W tile

    int tid  = threadIdx.x;
    int wave = tid >> 6;
    int lane = tid & 63;
    int quad = lane >> 4;
    int l16  = lane & 15;
    int g0   = bid * 2;
    int row0 = bid * 64;

    if (tid < 128) {
        float s = in_stats[tid], ss = in_stats[128 + tid];
        float mn = s * inv_sM;
        sm->pmv[tid] = mn;
        sm->pmv[128 + tid] = rsqrtf(ss * inv_sM - mn * mn + BN_EPS);
    }
    if (tid < 66) {
        int gl = tid / 33, idx = tid - gl * 33;
        sm->rs[gl][idx] = row_start[(g0 + gl) * 33 + idx];
    }
    if (tid >= 128) {
        int t = tid - 128;
        sm->ci[t >> 6][t & 63] = col_idx[(g0 + (t >> 6)) * EPG + (t & 63)];
    }
    for (int i = tid; i < 128 * 32; i += 256) {
        int n = i >> 5, k = (i & 31) * 4;
        *(us4*)&sm->wsl[n * 136 + k] = *(const us4*)&Wt[(size_t)n * 128 + k];
    }
    __syncthreads();

    bf16x8 afrag[4];
    {
        const unsigned short* ap = uin + (size_t)(row0 + wave * 16 + l16) * 128;
        #pragma unroll
        for (int ks = 0; ks < 4; ++ks) {
            int kb = ks * 32 + quad * 8;
            float v[8];
            bf2f8(*(const bf16x8*)(const void*)&ap[kb], v);
            #pragma unroll
            for (int j = 0; j < 8; ++j)
                v[j] = (fmaxf(v[j], 0.f) - sm->pmv[kb + j]) * sm->pmv[128 + kb + j];
            afrag[ks] = quant8(v);
        }
    }

    f32x4 acc[8];
    #pragma unroll
    for (int j = 0; j < 8; ++j) acc[j] = (f32x4){0.f, 0.f, 0.f, 0.f};
    #pragma unroll
    for (int ks = 0; ks < 4; ++ks) {
        int kb = ks * 32 + quad * 8;
        #pragma unroll
        for (int nt = 0; nt < 8; ++nt) {
            bf16x8 b = *(const bf16x8*)(const void*)&sm->wsl[(nt * 16 + l16) * 136 + kb];
            acc[nt] = __builtin_amdgcn_mfma_f32_16x16x32_bf16(afrag[ks], b, acc[nt], 0, 0, 0);
        }
    }
    __syncthreads();   // ALL waves done reading W -> overlay safe

    #pragma unroll
    for (int nt = 0; nt < 8; ++nt) {
        int col = nt * 16 + l16;
        #pragma unroll
        for (int r = 0; r < 4; ++r)
            zt[(wave * 16 + quad * 4 + r) * 132 + col] = acc[nt][r];
    }
    __syncthreads();

    float sv[4] = {0.f, 0.f, 0.f, 0.f}, qv[4] = {0.f, 0.f, 0.f, 0.f};
    {
        int c4  = (tid & 31) * 4;
        int rg  = tid >> 5;
        int hh  = rg >> 2;
        int rb0 = (rg & 3) * 8;
        float4 bv = *(const float4*)&bias[c4];
        unsigned short* ub = uout + (size_t)row0 * 128;
        for (int rr = 0; rr < 8; ++rr) {
            int r = rb0 + rr;
            int lr = hh * 32 + r;
            float4 val = *(const float4*)&zt[lr * 132 + c4];
            int e0 = sm->rs[hh][r], e1 = sm->rs[hh][r + 1];
            for (int e = e0; e < e1; ++e) {
                float4 zz = *(const float4*)&zt[(hh * 32 + sm->ci[hh][e]) * 132 + c4];
                val.x += zz.x; val.y += zz.y; val.z += zz.z; val.w += zz.w;
            }
            float u0 = val.x + bv.x, u1 = val.y + bv.y;
            float u2 = val.z + bv.z, u3 = val.w + bv.w;
            *(us4*)&ub[(size_t)lr * 128 + c4] =
                (us4){ f2bf(u0), f2bf(u1), f2bf(u2), f2bf(u3) };
            sv[0] += u0; sv[1] += u1; sv[2] += u2; sv[3] += u3;
            qv[0] += u0 * u0; qv[1] += u1 * u1; qv[2] += u2 * u2; qv[3] += u3 * u3;
        }
    }
    __syncthreads();
    {
        int c4 = (tid & 31) * 4, rg = tid >> 5;
        #pragma unroll
        for (int j = 0; j < 4; ++j) {
            zt[rg * 128 + c4 + j] = sv[j];
            zt[1024 + rg * 128 + c4 + j] = qv[j];
        }
    }
    __syncthreads();
    if (tid < 128) {
        float s = 0.f, q = 0.f;
        #pragma unroll
        for (int rg = 0; rg < 8; ++rg) {
            s += zt[rg * 128 + tid];
            q += zt[1024 + rg * 128 + tid];
        }
        part[(size_t)bid * 256 + tid] = s;
        part[(size_t)bid * 256 + 128 + tid] = q;
    }
}

// ---------------------------------------------------------------------------
// gin_lin body (streaming GEMM, W LDS tile)
// ---------------------------------------------------------------------------
struct LinSmem {
    unsigned short Ws_l[128 * 136];
    float pmv[256];
    float red[4][2][128];
};

template<int DO_POOL>
__device__ void dev_gin_lin(LinSmem* sm, int bid,
                            const unsigned short* __restrict__ uin,
                            const unsigned short* __restrict__ Wt,
                            const float* __restrict__ bias,
                            const float* __restrict__ in_stats, float inv_sM,
                            unsigned short* uout,
                            float* __restrict__ part,
                            float* __restrict__ pool_out)
{
    int tid  = threadIdx.x;
    int wave = tid >> 6;
    int lane = tid & 63;
    int quad = lane >> 4;
    int l16  = lane & 15;
    int row0 = bid * 64;

    for (int i = tid; i < 128 * 32; i += 256) {
        int n = i >> 5, k = (i & 31) * 4;
        *(us4*)&sm->Ws_l[n * 136 + k] = *(const us4*)&Wt[(size_t)n * 128 + k];
    }
    if (tid < 128) {
        float s = in_stats[tid], ss = in_stats[128 + tid];
        float mn = s * inv_sM;
        sm->pmv[tid] = mn;
        sm->pmv[128 + tid] = rsqrtf(ss * inv_sM - mn * mn + BN_EPS);
    }
    __syncthreads();

    bf16x8 afrag[4];
    {
        const unsigned short* ap = uin + (size_t)(row0 + wave * 16 + l16) * 128;
        #pragma unroll
        for (int ks = 0; ks < 4; ++ks) {
            int kb = ks * 32 + quad * 8;
            float v[8];
            bf2f8(*(const bf16x8*)(const void*)&ap[kb], v);
            #pragma unroll
            for (int j = 0; j < 8; ++j)
                v[j] = fmaxf((v[j] - sm->pmv[kb + j]) * sm->pmv[128 + kb + j], 0.f);
            afrag[ks] = quant8(v);
        }
    }

    f32x4 acc[8];
    #pragma unroll
    for (int j = 0; j < 8; ++j) acc[j] = (f32x4){0.f, 0.f, 0.f, 0.f};
    #pragma unroll
    for (int ks = 0; ks < 4; ++ks) {
        int kb = ks * 32 + quad * 8;
        #pragma unroll
        for (int nt = 0; nt < 8; ++nt) {
            bf16x8 b = *(const bf16x8*)(const void*)&sm->Ws_l[(nt * 16 + l16) * 136 + kb];
            acc[nt] = __builtin_amdgcn_mfma_f32_16x16x32_bf16(afrag[ks], b, acc[nt], 0, 0, 0);
        }
    }

    float ls[8], lq[8], lm[8];
    #pragma unroll
    for (int nt = 0; nt < 8; ++nt) {
        int col = nt * 16 + l16;
        float bv = bias[col];
        int rb = row0 + wave * 16 + quad * 4;
        float s0 = 0.f, q0 = 0.f, mx = -INFINITY;
        #pragma unroll
        for (int r = 0; r < 4; ++r) {
            float u = acc[nt][r] + bv;
            float ru = fmaxf(u, 0.f);
            s0 += ru; q0 += ru * ru;
            if (DO_POOL) mx = fmaxf(mx, ru);
            else uout[(size_t)(rb + r) * 128 + col] = f2bf(u);
        }
        ls[nt] = s0; lq[nt] = q0; lm[nt] = mx;
    }

    #pragma unroll
    for (int nt = 0; nt < 8; ++nt) {
        float s = ls[nt], q = lq[nt];
        s += __shfl_xor(s, 16); q += __shfl_xor(q, 16);
        s += __shfl_xor(s, 32); q += __shfl_xor(q, 32);
        if (quad == 0) {
            sm->red[wave][0][nt * 16 + l16] = s;
            sm->red[wave][1][nt * 16 + l16] = q;
        }
    }
    __syncthreads();
    if (tid < 128) {
        float s = sm->red[0][0][tid] + sm->red[1][0][tid] + sm->red[2][0][tid] + sm->red[3][0][tid];
        float q = sm->red[0][1][tid] + sm->red[1][1][tid] + sm->red[2][1][tid] + sm->red[3][1][tid];
        part[(size_t)bid * 256 + tid] = s;
        part[(size_t)bid * 256 + 128 + tid] = q;
    }
    if (DO_POOL) {
        __syncthreads();
        #pragma unroll
        for (int nt = 0; nt < 8; ++nt) {
            float m = lm[nt];
            m = fmaxf(m, __shfl_xor(m, 16));
            m = fmaxf(m, __shfl_xor(m, 32));
            if (quad == 0) sm->red[wave][0][nt * 16 + l16] = m;
        }
        __syncthreads();
        {
            int gi = tid >> 7, col = tid & 127;
            float m = fmaxf(sm->red[gi * 2][0][col], sm->red[gi * 2 + 1][0][col]);
            pool_out[(size_t)((row0 >> 5) + gi) * 128 + col] = m;
        }
    }
}

// ---------------------------------------------------------------------------
// gemm_rB body (16-row blocks, W direct from L2)
// ---------------------------------------------------------------------------
struct RBSmem { float pm[256]; float pv[256]; };

template<int KSTEPS, int NT>
__device__ void dev_rB(RBSmem* sm, int bid,
                       const float* __restrict__ A, const float* __restrict__ A2,
                       int lda, int K, int stats_K, int ksplit,
                       const unsigned short* __restrict__ Wt,
                       const float* __restrict__ bias, float* __restrict__ C,
                       const float* __restrict__ in_stats, float inv_sM, int in_mode,
                       float* __restrict__ part, int stats_mode, int out_act)
{
    constexpr int NSUBW = NT / 64;
    int tid  = threadIdx.x;
    int wave = tid >> 6;
    int lane = tid & 63;
    int quad = lane >> 4;
    int l16  = lane & 15;
    int m0   = bid * 16;

    if (in_mode) {
        for (int k = tid; k < KSTEPS * 32; k += 256) {
            float mn = 0.f, iv = 1.f;
            if (k < stats_K) {
                float s = in_stats[k], ss = in_stats[stats_K + k];
                mn = s * inv_sM;
                float vr = ss * inv_sM - mn * mn;
                iv = rsqrtf(vr + BN_EPS);
            }
            sm->pm[k] = mn; sm->pv[k] = iv;
        }
        __syncthreads();
    }

    bf16x8 afrag[KSTEPS];
    {
        int row = m0 + l16;
        const float* ap = A + (size_t)row * lda;
        #pragma unroll
        for (int ks = 0; ks < KSTEPS; ++ks) {
            int kb = ks * 32 + quad * 8;
            float v[8];
            #pragma unroll
            for (int hh = 0; hh < 2; ++hh) {
                int k = kb + hh * 4;
                const float* p = (k >= ksplit) ? &A2[(size_t)row * 128 + (k - 128)]
                                               : &ap[k];
                float4 f = *(const float4*)p;
                v[hh * 4 + 0] = f.x; v[hh * 4 + 1] = f.y;
                v[hh * 4 + 2] = f.z; v[hh * 4 + 3] = f.w;
            }
            if (in_mode) {
                #pragma unroll
                for (int j = 0; j < 8; ++j)
                    v[j] = apply_in(v[j], in_mode, sm->pm[kb + j], sm->pv[kb + j]);
            }
            afrag[ks] = quant8(v);
        }
    }

    f32x4 acc[NSUBW];
    #pragma unroll
    for (int j = 0; j < NSUBW; ++j) acc[j] = (f32x4){0.f, 0.f, 0.f, 0.f};

    #pragma unroll
    for (int ks = 0; ks < KSTEPS; ++ks) {
        #pragma unroll
        for (int nt = 0; nt < NSUBW; ++nt) {
            int wrow = (wave * NSUBW + nt) * 16 + l16;
            bf16x8 b = *(const bf16x8*)(const void*)&Wt[(size_t)wrow * K + ks * 32 + quad * 8];
            acc[nt] = __builtin_amdgcn_mfma_f32_16x16x32_bf16(afrag[ks], b, acc[nt], 0, 0, 0);
        }
    }

    float ls[NSUBW], lq[NSUBW];
    #pragma unroll
    for (int nt = 0; nt < NSUBW; ++nt) { ls[nt] = 0.f; lq[nt] = 0.f; }

    #pragma unroll
    for (int nt = 0; nt < NSUBW; ++nt) {
        int col = (wave * NSUBW + nt) * 16 + l16;
        float bv = bias[col];
        int rbase = m0 + quad * 4;
        #pragma unroll
        for (int r = 0; r < 4; ++r) {
            float u = acc[nt][r] + bv;
            if (C) {
                float wv = out_act ? fmaxf(u, 0.f) : u;
                C[(size_t)(rbase + r) * NT + col] = wv;
            }
            if (stats_mode) {
                float s = (stats_mode == 2) ? fmaxf(u, 0.f) : u;
                ls[nt] += s; lq[nt] += s * s;
            }
        }
    }

    if (stats_mode) {
        #pragma unroll
        for (int nt = 0; nt < NSUBW; ++nt) {
            float s = ls[nt], q = lq[nt];
            s += __shfl_xor(s, 16); q += __shfl_xor(q, 16);
            s += __shfl_xor(s, 32); q += __shfl_xor(q, 32);
            if (quad == 0) {
                int col = (wave * NSUBW + nt) * 16 + l16;
                part[(size_t)bid * 256 + col] = s;
                part[(size_t)bid * 256 + 128 + col] = q;
            }
        }
    }
}

// ---------------------------------------------------------------------------
// gemm_cell body (software-pipelined, K-chunk 128, tile 32 x NT), flattened:
// bid -> m0 = (bid & 255)*32, n-block = bid >> 8.
// ---------------------------------------------------------------------------
template<int NT>
struct CellSmem {
    unsigned short As_l[32 * 136];
    unsigned short Ws_l[NT * 136];
    float red[2][2][NT];
};

template<int NT>
__device__ void dev_gemm_cell(CellSmem<NT>* sm, int bid,
                              const unsigned short* __restrict__ Abf, int abf_str,
                              const unsigned short* __restrict__ Wt,
                              const float* __restrict__ bias, float* __restrict__ C,
                              int K, int N, float* __restrict__ out_stats)
{
    constexpr int NSUB = NT / 32;
    constexpr int WITEMS = NT * 32 / 256;
    int tid = threadIdx.x;
    int wave = tid >> 6;
    int lane = tid & 63;
    int quad = lane >> 4;
    int l16 = lane & 15;
    int mhalf = wave & 1, nhalf = wave >> 1;
    int m0 = (bid & 255) * 32, n0 = (bid >> 8) * NT;

    us8 aReg[2];
    us4 wReg[WITEMS];

    auto loadA = [&](int k0) {
        #pragma unroll
        for (int t = 0; t < 2; ++t) {
            int i = t * 256 + tid;
            int row = i >> 4, c8 = (i & 15) * 8;
            aReg[t] = *(const us8*)&Abf[(size_t)(m0 + row) * abf_str + k0 + c8];
        }
    };
    auto loadW = [&](int k0) {
        #pragma unroll
        for (int t = 0; t < WITEMS; ++t) {
            int i = t * 256 + tid;
            int nn = i >> 5, kt = i & 31;
            int k = k0 + kt * 4;
            int gn = n0 + nn;
            us4 w4 = (us4){0, 0, 0, 0};
            if (gn < N && k < K) w4 = *(const us4*)&Wt[(size_t)gn * K + k];
            wReg[t] = w4;
        }
    };
    auto storeAW = [&]() {
        #pragma unroll
        for (int t = 0; t < 2; ++t) {
            int i = t * 256 + tid;
            int row = i >> 4, c8 = (i & 15) * 8;
            *(us8*)&sm->As_l[row * 136 + c8] = aReg[t];
        }
        #pragma unroll
        for (int t = 0; t < WITEMS; ++t) {
            int i = t * 256 + tid;
            int nn = i >> 5, kt = i & 31;
            *(us4*)&sm->Ws_l[nn * 136 + kt * 4] = wReg[t];
        }
    };

    f32x4 acc[NSUB];
    #pragma unroll
    for (int j = 0; j < NSUB; ++j) acc[j] = (f32x4){0.f, 0.f, 0.f, 0.f};

    int nch = (K + 127) >> 7;
    loadA(0); loadW(0);
    for (int c = 0; c < nch; ++c) {
        storeAW();
        if (c + 1 < nch) { loadA((c + 1) * 128); loadW((c + 1) * 128); }
        __syncthreads();
        #pragma unroll
        for (int ks = 0; ks < 4; ++ks) {
            bf16x8 a = *(const bf16x8*)(const void*)
                &sm->As_l[(mhalf * 16 + l16) * 136 + ks * 32 + quad * 8];
            #pragma unroll
            for (int nt = 0; nt < NSUB; ++nt) {
                bf16x8 b = *(const bf16x8*)(const void*)
                    &sm->Ws_l[(nhalf * (NT / 2) + nt * 16 + l16) * 136 + ks * 32 + quad * 8];
                acc[nt] = __builtin_amdgcn_mfma_f32_16x16x32_bf16(a, b, acc[nt], 0, 0, 0);
            }
        }
        __syncthreads();
    }

    float ls[NSUB], lq[NSUB];
    #pragma unroll
    for (int nt = 0; nt < NSUB; ++nt) { ls[nt] = 0.f; lq[nt] = 0.f; }

    #pragma unroll
    for (int nt = 0; nt < NSUB; ++nt) {
        int col = n0 + nhalf * (NT / 2) + nt * 16 + l16;
        if (col < N) {
            float bv = bias[col];
            int rbase = m0 + mhalf * 16 + quad * 4;
            #pragma unroll
            for (int r = 0; r < 4; ++r) {
                float u = acc[nt][r] + bv;
                C[(size_t)(rbase + r) * N + col] = u;
                ls[nt] += u; lq[nt] += u * u;
            }
        }
    }

    #pragma unroll
    for (int nt = 0; nt < NSUB; ++nt) {
        float s = ls[nt], q = lq[nt];
        s += __shfl_xor(s, 16); q += __shfl_xor(q, 16);
        s += __shfl_xor(s, 32); q += __shfl_xor(q, 32);
        if (quad == 0) {
            int lc = nhalf * (NT / 2) + nt * 16 + l16;
            sm->red[mhalf][0][lc] = s;
            sm->red[mhalf][1][lc] = q;
        }
    }
    __syncthreads();
    if (tid < NT) {
        int col = n0 + tid;
        if (col < N) {
            float s = sm->red[0][0][tid] + sm->red[1][0][tid];
            float q = sm->red[0][1][tid] + sm->red[1][1][tid];
            unsafeAtomicAdd(&out_stats[col], s);
            unsafeAtomicAdd(&out_stats[N + col], q);
        }
    }
}

// ===========================================================================
// Fused kernels (block-range dispatch; LDS = union of branch needs)
// ===========================================================================
__global__ __launch_bounds__(256)
void prep(TransArgs ta, SetupArgs sa, const float* cell, unsigned short* abf,
          int nbT, int nbZC)
{
    __shared__ __align__(16) char smem[sizeof(TransSmem)];
    int b = blockIdx.x;
    if (b < nbT) { dev_transpose((TransSmem*)smem, b, ta); return; }
    b -= nbT;
    if (b < nbZC) { dev_setup((SetupSmem*)smem, b, sa); return; }
    b -= nbZC;
    dev_quant_cell(b, cell, abf);
}

__global__ __launch_bounds__(256)
void gin_s1_k(const float* drug_x, const int* row_start, const int* col_idx,
              const unsigned short* W11, const float* b11,
              unsigned short* uout, float* partA)
{
    __shared__ __align__(16) char smem[sizeof(S1Smem)];
    dev_gin_s1((S1Smem*)smem, blockIdx.x, drug_x, row_start, col_idx,
               W11, b11, uout, partA);
}

// lin0 (GIN stage 2) + ce1 (cell layer 1) -- the two longest independent pools
__global__ __launch_bounds__(256)
void f_lin0_ce1(const unsigned short* uin, const unsigned short* Wt4,
                const float* g12b, const float* st_u1, float inv_N,
                unsigned short* uout, float* partA,
                const unsigned short* Abf, const unsigned short* Wt0,
                const float* ce1b, float* c1, float* st_c1, int nb1)
{
    constexpr size_t SZ = sizeof(LinSmem) > sizeof(CellSmem<128>)
                        ? sizeof(LinSmem) : sizeof(CellSmem<128>);
    __shared__ __align__(16) char smem[SZ];
    int b = blockIdx.x;
    if (b < nb1)
        dev_gin_lin<0>((LinSmem*)smem, b, uin, Wt4, g12b, st_u1, inv_N,
                       uout, partA, nullptr);
    else
        dev_gemm_cell<128>((CellSmem<128>*)smem, b - nb1, Abf, ABF_STR, Wt0,
                           ce1b, c1, CELLD, 516, st_c1);
}

__global__ __launch_bounds__(256)
void f_red_qc1(const float* partA, int nrows, float* out,
               const float* c1, const float* st_c1, float inv_B,
               unsigned short* c1bf, int nb1)
{
    int b = blockIdx.x;
    if (b < nb1) dev_reduce(b, partA, nrows, 128, out);
    else dev_quant_c1(b - nb1, c1, st_c1, inv_B, c1bf);
}

// s3f (GIN stage 3) + ce2 (cell layer 2)
__global__ __launch_bounds__(256)
void f_s3f_ce2(const unsigned short* uin, const int* row_start, const int* col_idx,
               const unsigned short* Wt5, const float* g21b,
               const float* st_u2rel, float inv_N, unsigned short* uout,
               float* partA,
               const unsigned short* C1bf, const unsigned short* Wt1,
               const float* ce2b, float* c2, float* st_c2, int nb1)
{
    constexpr size_t SZ = sizeof(S3fSmem) > sizeof(CellSmem<64>)
                        ? sizeof(S3fSmem) : sizeof(CellSmem<64>);
    __shared__ __align__(16) char smem[SZ];
    int b = blockIdx.x;
    if (b < nb1)
        dev_gin_s3f((S3fSmem*)smem, b, uin, row_start, col_idx, Wt5, g21b,
                    st_u2rel, inv_N, uout, partA);
    else
        dev_gemm_cell<64>((CellSmem<64>*)smem, b - nb1, C1bf, C1_STR, Wt1,
                          ce2b, c2, 516, 256, st_c2);
}

// lin1 (GIN stage 4 + pool) + ce3 (cell layer 3, rB form writing partB)
__global__ __launch_bounds__(256)
void f_lin1_ce3(const unsigned short* uin, const unsigned short* Wt6,
                const float* g22b, const float* st_u3, float inv_N,
                float* partA, float* pool_out,
                const float* c2, const unsigned short* Wt2, const float* ce3b,
                float* c3u, const float* st_c2, float inv_B, float* partB, int nb1)
{
    constexpr size_t SZ = sizeof(LinSmem) > sizeof(RBSmem)
                        ? sizeof(LinSmem) : sizeof(RBSmem);
    __shared__ __align__(16) char smem[SZ];
    int b = blockIdx.x;
    if (b < nb1)
        dev_gin_lin<1>((LinSmem*)smem, b, uin, Wt6, g22b, st_u3, inv_N,
                       nullptr, partA, pool_out);
    else
        dev_rB<8, 128>((RBSmem*)smem, b - nb1, c2, nullptr, 256, 256, 256,
                       1 << 30, Wt2, ce3b, c3u, st_c2, inv_B, 1, partB, 1, 0);
}

__global__ __launch_bounds__(256)
void f_red2(const float* partA, int nrowsA, float* outA,
            const float* partB, int nrowsB, float* outB)
{
    int b = blockIdx.x;
    if (b < 64) dev_reduce(b, partA, nrowsA, 128, outA);
    else dev_reduce(b - 64, partB, nrowsB, 128, outB);
}

// ===========================================================================
// Standalone kernels
// ===========================================================================
__global__ __launch_bounds__(256)
void reduce_stats(const float* __restrict__ part, int nrows, int nt,
                  float* __restrict__ out)
{
    dev_reduce(blockIdx.x, part, nrows, nt, out);
}

template<int KSTEPS, int NT>
__global__ __launch_bounds__(256)
void gemm_rB(const float* A, const float* A2, int lda, int K, int stats_K,
             int ksplit, const unsigned short* Wt, const float* bias, float* C,
             const float* in_stats, float inv_sM, int in_mode,
             float* part, int stats_mode, int out_act)
{
    __shared__ __align__(16) char smem[sizeof(RBSmem)];
    dev_rB<KSTEPS, NT>((RBSmem*)smem, blockIdx.x, A, A2, lda, K, stats_K, ksplit,
                       Wt, bias, C, in_stats, inv_sM, in_mode, part, stats_mode, out_act);
}

__global__ void final_dot(const float* __restrict__ u, const float* __restrict__ w,
                          const float* __restrict__ b, float* __restrict__ y,
                          const float* __restrict__ stats, float inv_sM)
{
    __shared__ float pmv[64], piv[64], sw[64];
    int tid = threadIdx.x;
    if (tid < 64) {
        float s = stats[tid], ss = stats[64 + tid];
        float mn = s * inv_sM;
        float vr = ss * inv_sM - mn * mn;
        pmv[tid] = mn;
        piv[tid] = rsqrtf(vr + BN_EPS);
        sw[tid] = w[tid];
    }
    __syncthreads();
    int i = blockIdx.x * blockDim.x + tid;
    if (i >= BGRAPH) return;
    float acc = 0.f;
    #pragma unroll
    for (int k = 0; k < 64; ++k) {
        float v = (u[(size_t)i * 64 + k] - pmv[k]) * piv[k];
        v = (v > 0.f) ? v : expm1f(v);
        acc += v * sw[k];
    }
    y[i] = acc + b[0];
}

// ---------------------------------------------------------------------------
// Host driver. 16 launches; balanced GIN/cell fusion pairs.
// ---------------------------------------------------------------------------
extern "C" void kernel_launch(void* const* d_in, const int* in_sizes, int n_in,
                              void* d_out, int out_size, void* d_ws, size_t ws_size,
                              hipStream_t stream)
{
    const float* cell   = (const float*)d_in[0];
    const float* drug_x = (const float*)d_in[1];
    const int*   eidx   = (const int*)d_in[2];
    const float* ce1w = (const float*)d_in[4];  const float* ce1b = (const float*)d_in[5];
    const float* ce2w = (const float*)d_in[6];  const float* ce2b = (const float*)d_in[7];
    const float* ce3w = (const float*)d_in[8];  const float* ce3b = (const float*)d_in[9];
    const float* g11w = (const float*)d_in[10]; const float* g11b = (const float*)d_in[11];
    const float* g12w = (const float*)d_in[12]; const float* g12b = (const float*)d_in[13];
    const float* g21w = (const float*)d_in[14]; const float* g21b = (const float*)d_in[15];
    const float* g22w = (const float*)d_in[16]; const float* g22b = (const float*)d_in[17];
    const float* d1w  = (const float*)d_in[18]; const float* d1b  = (const float*)d_in[19];
    const float* d2w  = (const float*)d_in[20]; const float* d2b  = (const float*)d_in[21];
    const float* f1w  = (const float*)d_in[22]; const float* f1b  = (const float*)d_in[23];
    const float* f2w  = (const float*)d_in[24]; const float* f2b  = (const float*)d_in[25];
    const float* f3w  = (const float*)d_in[26]; const float* f3b  = (const float*)d_in[27];

    const int* src = eidx;
    const int* dst = eidx + NEDGE;
    float* out = (float*)d_out;

    const float INV_N = 1.f / (float)NNODE;
    const float INV_B = 1.f / (float)BGRAPH;
    const int KBIG = 1 << 30;

    // ---- workspace layout ----
    float* ws = (float*)d_ws;
    unsigned short* ubg = (unsigned short*)ws;            // NNODE*128 ushorts
    float* pbuf = ws + (size_t)NNODE * 64;                // BGRAPH*128 floats
    float* sb   = pbuf + (size_t)BGRAPH * 128;            // 10*1032 stats floats
    unsigned short* wtb = (unsigned short*)(sb + 10 * 1032);
    auto ST = [&](int i) { return sb + (size_t)i * 1032; };
    float* st_u1    = ST(0);
    float* st_u2rel = ST(1);
    float* st_u3    = ST(2);
    float* st_u4rel = ST(3);
    float* st_c1    = ST(4);
    float* st_c2    = ST(5);
    float* st_c3    = ST(6);
    float* st_d1    = ST(7);
    float* st_f1    = ST(8);
    float* st_f2    = ST(9);

    struct WDef { const float* w; int K; int N; };
    WDef wd[11] = {
        {ce1w, CELLD, 516}, {ce2w, 516, 256}, {ce3w, 256, 128},
        {g11w, 9, 128}, {g12w, 128, 128}, {g21w, 128, 128}, {g22w, 128, 128},
        {d1w, 128, 128}, {d2w, 128, 128}, {f1w, 256, 128}, {f2w, 128, 64}
    };
    TransArgs ta;
    int off = 0;
    unsigned short* wt[11];
    ta.off[0] = 0;
    for (int i = 0; i < 11; ++i) {
        wt[i] = wtb + off;
        ta.w[i] = wd[i].w; ta.wt[i] = wt[i];
        ta.K[i] = wd[i].K; ta.N[i] = wd[i].N;
        ta.ntN[i] = (wd[i].N + 63) / 64;
        ta.off[i + 1] = ta.off[i] + ((wd[i].K + 63) / 64) * ta.ntN[i];
        off += wd[i].K * wd[i].N;
    }

    SetupArgs sa;
    sa.zb = sb; sa.zTotal = 10 * 1032; sa.zBlocks = (10 * 1032 + 255) / 256;
    sa.src = src; sa.dst = dst;

    int csr_off = (off + 7) & ~7;
    int* row_start = (int*)(wtb + csr_off);
    int* col_idx   = row_start + (size_t)BGRAPH * 33;
    float* partA = (float*)(col_idx + (size_t)NEDGE);      // 4096*256 floats
    float* partB = partA + (size_t)4096 * 256;             // 512*256 floats
    unsigned short* Abf  = (unsigned short*)(partB + (size_t)512 * 256);
    unsigned short* C1bf = Abf + (size_t)BGRAPH * ABF_STR;
    // fresh fp32 cell region: c1 (8192x516) lives here until quant_c1 (L4);
    // c2 (8192x256) overlays it afterwards; c3u disjoint from c2.
    float* cellws = (float*)(C1bf + (size_t)BGRAPH * C1_STR);
    float* c1  = cellws;
    float* c2  = cellws;
    float* c3u = cellws + (size_t)BGRAPH * 256;
    // d/head buffers alias ubg (dead after lin1)
    float* dbuf  = ws;
    float* d2buf = dbuf + (size_t)BGRAPH * 128;
    float* f1o   = d2buf + (size_t)BGRAPH * 128;
    float* f2o   = f1o + (size_t)BGRAPH * 128;
    sa.row_start = row_start; sa.col_idx = col_idx;

    int nbT = ta.off[11];
    int nbZC = sa.zBlocks + BGRAPH / 4;

    // L0: transpose + zero + CSR + quant_cell (all independent)
    prep<<<nbT + nbZC + 8192, 256, 0, stream>>>(ta, sa, cell, Abf, nbT, nbZC);

    // L1: gin_s1 alone (slim LDS)
    gin_s1_k<<<BGRAPH / 4, 256, 0, stream>>>(
        drug_x, row_start, col_idx, wt[3], g11b, ubg, partA);

    // L2: reduce u1
    reduce_stats<<<64, 256, 0, stream>>>(partA, BGRAPH / 4, 128, st_u1);

    // L3: lin0 (4096) + ce1 (1280) -- the two long pools overlapped
    f_lin0_ce1<<<4096 + 1280, 256, 0, stream>>>(
        ubg, wt[4], g12b, st_u1, INV_N, ubg, partA,
        Abf, wt[0], ce1b, c1, st_c1, 4096);

    // L4: reduce u2rel (64) + quant_c1 (5120)
    f_red_qc1<<<64 + 5120, 256, 0, stream>>>(
        partA, NNODE / 64, st_u2rel, c1, st_c1, INV_B, C1bf, 64);

    // L5: gin_s3f (4096) + ce2 (1024)
    f_s3f_ce2<<<4096 + 1024, 256, 0, stream>>>(
        ubg, row_start, col_idx, wt[5], g21b, st_u2rel, INV_N, ubg, partA,
        C1bf, wt[1], ce2b, c2, st_c2, 4096);

    // L6: reduce u3
    reduce_stats<<<64, 256, 0, stream>>>(partA, BGRAPH / 2, 128, st_u3);

    // L7: gin_lin1 (4096, pool) + ce3 (512, rB -> partB)
    f_lin1_ce3<<<4096 + 512, 256, 0, stream>>>(
        ubg, wt[6], g22b, st_u3, INV_N, partA, pbuf,
        c2, wt[2], ce3b, c3u, st_c2, INV_B, partB, 4096);

    // L8: reduce u4rel (64) + reduce partB -> st_c3 (64)
    f_red2<<<128, 256, 0, stream>>>(
        partA, NNODE / 64, st_u4rel, partB, BGRAPH / 16, st_c3);

    // ================= d branch ==============================================
    gemm_rB<4, 128><<<BGRAPH / 16, 256, 0, stream>>>(
        pbuf, nullptr, 128, 128, 128, KBIG, wt[7], d1b, dbuf,
        st_u4rel, INV_N, 3, partA, 1, 0);
    reduce_stats<<<64, 256, 0, stream>>>(partA, BGRAPH / 16, 128, st_d1);
    gemm_rB<4, 128><<<BGRAPH / 16, 256, 0, stream>>>(
        dbuf, nullptr, 128, 128, 128, KBIG, wt[8], d2b, d2buf,
        st_d1, INV_B, 1, partA, 0, 1);

    // ================= head ==================================================
    gemm_rB<8, 128><<<BGRAPH / 16, 256, 0, stream>>>(
        c3u, d2buf, 128, 256, 128, 128, wt[9], f1b, f1o,
        st_c3, INV_B, 1, partA, 1, 0);
    reduce_stats<<<64, 256, 0, stream>>>(partA, BGRAPH / 16, 128, st_f1);
    gemm_rB<4, 64><<<BGRAPH / 16, 256, 0, stream>>>(
        f1o, nullptr, 128, 128, 128, KBIG, wt[10], f2b, f2o,
        st_f1, INV_B, 2, partA, 1, 0);
    reduce_stats<<<64, 256, 0, stream>>>(partA, BGRAPH / 16, 64, st_f2);
    final_dot<<<BGRAPH / 256, 256, 0, stream>>>(f2o, f3w, f3b, out, st_f2, INV_B);
}

// Round 15
// 517.860 us; speedup vs baseline: 1.0340x; 1.0340x over previous
//
#include <hip/hip_runtime.h>
#include <hip/hip_bf16.h>
#include <math.h>

// Problem constants (from reference)
#define BGRAPH 8192
#define NPG 32
#define EPG 64
#define NNODE (BGRAPH * NPG)   // 262144
#define NEDGE (BGRAPH * EPG)   // 524288
#define CELLD 908
#define BN_EPS 1e-5f
#define ABF_STR 1024           // bf16 cell row stride (zero-padded, mult of 128)
#define C1_STR 640             // bf16 c1 row stride (516 padded to mult of 128)
#define HBS 136

typedef __attribute__((ext_vector_type(8))) short bf16x8;   // 8 bf16 = 4 VGPRs
typedef __attribute__((ext_vector_type(4))) float f32x4;
typedef __attribute__((ext_vector_type(4))) unsigned short us4;
typedef __attribute__((ext_vector_type(8))) unsigned short us8;

__device__ __forceinline__ unsigned short f2bf(float f)
{
    unsigned int u = __float_as_uint(f);
    u = (u + 0x7FFFu + ((u >> 16) & 1u)) >> 16;   // RNE
    return (unsigned short)u;
}

__device__ __forceinline__ bf16x8 quant8(const float v[8])
{
    union { bf16x8 b; unsigned short u[8]; } fr;
    #pragma unroll
    for (int j = 0; j < 8; ++j) fr.u[j] = f2bf(v[j]);
    return fr.b;
}

__device__ __forceinline__ void bf2f8(bf16x8 b, float v[8])
{
    union { bf16x8 bb; unsigned short u[8]; } x; x.bb = b;
    #pragma unroll
    for (int j = 0; j < 8; ++j) v[j] = __uint_as_float((unsigned)x.u[j] << 16);
}

// in_mode: 0=raw, 1=relu((x-m)*iv), 2=elu((x-m)*iv), 3=(relu(x)-m)*iv
__device__ __forceinline__ float apply_in(float v, int mode, float mn, float iv)
{
    if (mode == 1)      { v = (v - mn) * iv; v = fmaxf(v, 0.f); }
    else if (mode == 2) { v = (v - mn) * iv; v = (v > 0.f) ? v : expm1f(v); }
    else if (mode == 3) { v = fmaxf(v, 0.f); v = (v - mn) * iv; }
    return v;
}

// ===========================================================================
// Device bodies (shared-memory passed in so fused kernels can union them)
// ===========================================================================
struct TransArgs {
    const float* w[11];
    unsigned short* wt[11];
    int K[11], N[11], ntN[11];
    int off[12];
};
struct TransSmem { float t[64][65]; };

__device__ void dev_transpose(TransSmem* sm, int b, const TransArgs& a)
{
    int tid = threadIdx.x;
    int s = 0;
    while (s < 10 && b >= a.off[s + 1]) ++s;
    int t0 = b - a.off[s];
    int K = a.K[s], N = a.N[s], ntn = a.ntN[s];
    int kt = t0 / ntn, nt = t0 - kt * ntn;
    int k0 = kt * 64, n0 = nt * 64;
    const float* w = a.w[s];
    unsigned short* wt = a.wt[s];
    int c = tid & 63, rg = tid >> 6;
    #pragma unroll
    for (int i = 0; i < 16; ++i) {
        int rr = rg * 16 + i;
        int k = k0 + rr, n = n0 + c;
        sm->t[c][rr] = (k < K && n < N) ? w[(size_t)k * N + n] : 0.f;
    }
    __syncthreads();
    #pragma unroll
    for (int i = 0; i < 16; ++i) {
        int rr = rg * 16 + i;
        int n = n0 + rr, k = k0 + c;
        if (n < N && k < K) wt[(size_t)n * K + k] = f2bf(sm->t[rr][c]);
    }
}

struct SetupArgs {
    float* zb; int zTotal; int zBlocks;
    const int* src; const int* dst; int* row_start; int* col_idx;
};
struct SetupSmem { int cnt[4][32]; int fill[4][32]; int rsl[4][33]; };

__device__ void dev_setup(SetupSmem* sm, int b, const SetupArgs& a)
{
    int tid = threadIdx.x;
    if (b < a.zBlocks) {
        int i = b * 256 + tid;
        if (i < a.zTotal) a.zb[i] = 0.f;
        return;
    }
    b -= a.zBlocks;
    int gl = tid >> 6, e = tid & 63;
    int g = b * 4 + gl;
    if (e < 32) { sm->cnt[gl][e] = 0; sm->fill[gl][e] = 0; }
    __syncthreads();
    int s = a.src[g * EPG + e] - g * NPG;
    int d = a.dst[g * EPG + e] - g * NPG;
    atomicAdd(&sm->cnt[gl][d], 1);
    __syncthreads();
    if (e == 0) {
        int acc = 0;
        for (int i = 0; i < 32; ++i) { sm->rsl[gl][i] = acc; acc += sm->cnt[gl][i]; }
        sm->rsl[gl][32] = acc;
    }
    __syncthreads();
    int pos = sm->rsl[gl][d] + atomicAdd(&sm->fill[gl][d], 1);
    a.col_idx[g * EPG + pos] = s;
    if (e < 33) a.row_start[g * 33 + e] = sm->rsl[gl][e];
}

__device__ void dev_quant_cell(int bid, const float* __restrict__ cell,
                               unsigned short* __restrict__ abf)
{
    int i = bid * 256 + threadIdx.x;
    int row = i / (ABF_STR / 4), c4 = i - row * (ABF_STR / 4);
    int k = c4 * 4;
    us4 w = (us4){0, 0, 0, 0};
    if (k < CELLD) {
        float4 f = *(const float4*)&cell[(size_t)row * CELLD + k];
        w = (us4){ f2bf(f.x), f2bf(f.y), f2bf(f.z), f2bf(f.w) };
    }
    *(us4*)&abf[(size_t)row * ABF_STR + k] = w;
}

__device__ void dev_quant_c1(int bid, const float* __restrict__ c1,
                             const float* __restrict__ stats, float inv_sM,
                             unsigned short* __restrict__ out)
{
    int i = bid * 256 + threadIdx.x;
    int row = i / (C1_STR / 4), c4 = i - row * (C1_STR / 4);
    int k = c4 * 4;
    us4 w = (us4){0, 0, 0, 0};
    if (k < 516) {
        float4 f = *(const float4*)&c1[(size_t)row * 516 + k];
        float v[4] = {f.x, f.y, f.z, f.w};
        #pragma unroll
        for (int j = 0; j < 4; ++j) {
            float s = stats[k + j], ss = stats[516 + k + j];
            float mn = s * inv_sM;
            float iv = rsqrtf(ss * inv_sM - mn * mn + BN_EPS);
            v[j] = fmaxf((v[j] - mn) * iv, 0.f);
        }
        w = (us4){ f2bf(v[0]), f2bf(v[1]), f2bf(v[2]), f2bf(v[3]) };
    }
    *(us4*)&out[(size_t)row * C1_STR + k] = w;
}

__device__ void dev_reduce(int bid, const float* __restrict__ part, int nrows,
                           int nt, float* __restrict__ out)
{
    int c = threadIdx.x;
    int per = nrows >> 6;
    int r0 = bid * per;
    bool isq = (c >= 128);
    int cc = isq ? c - 128 : c;
    if (cc >= nt) return;
    float s = 0.f;
    for (int r = 0; r < per; ++r) s += part[(size_t)(r0 + r) * 256 + c];
    unsafeAtomicAdd(&out[(isq ? nt : 0) + cc], s);
}

// ---------------------------------------------------------------------------
// gin_s1 body
// ---------------------------------------------------------------------------
struct S1Smem {
    unsigned short h[4 * 32 * HBS];
    unsigned char ubuf[4096];
    int rs[4][36];
    int ci[4][64];
};

__device__ void dev_gin_s1(S1Smem* sm, int bid,
                           const float* __restrict__ drug_x,
                           const int* __restrict__ row_start,
                           const int* __restrict__ col_idx,
                           const unsigned short* __restrict__ W11,
                           const float* __restrict__ b11,
                           unsigned short* uout, float* __restrict__ part)
{
    unsigned short* w11l = (unsigned short*)sm->ubuf;
    float* red = (float*)sm->ubuf;

    int tid  = threadIdx.x;
    int wave = tid >> 6;
    int lane = tid & 63;
    int quad = lane >> 4;
    int l16  = lane & 15;
    int g0   = bid * 4;
    unsigned short* hw = sm->h + wave * (32 * HBS);
    float* xw = (float*)hw;

    for (int i = tid; i < 128 * 16; i += 256) {
        int n = i >> 4, k = i & 15;
        w11l[i] = (k < 9) ? W11[n * 9 + k] : (unsigned short)0;
    }
    if (tid < 132) {
        int gl = tid / 33, idx = tid - gl * 33;
        sm->rs[gl][idx] = row_start[(g0 + gl) * 33 + idx];
    }
    {
        int gl = tid >> 6, e = tid & 63;
        sm->ci[gl][e] = col_idx[(g0 + gl) * EPG + e];
    }
    {
        const float* xg = drug_x + (size_t)(g0 + wave) * 32 * 9;
        for (int i = lane; i < 32 * 16; i += 64) {
            int rr = i >> 4, c = i & 15;
            xw[i] = (c < 9) ? xg[rr * 9 + c] : 0.f;
        }
    }
    __syncthreads();

    f32x4 acc[2][8];
    #pragma unroll
    for (int i = 0; i < 2; ++i)
        #pragma unroll
        for (int j = 0; j < 8; ++j)
            acc[i][j] = (f32x4){0.f, 0.f, 0.f, 0.f};

    {
        bf16x8 af[2];
        #pragma unroll
        for (int mt = 0; mt < 2; ++mt) {
            int rowl = mt * 16 + l16;
            float v[8] = {0, 0, 0, 0, 0, 0, 0, 0};
            if (quad < 2) {
                float4 lo = *(const float4*)&xw[rowl * 16 + quad * 8];
                float4 hi = *(const float4*)&xw[rowl * 16 + quad * 8 + 4];
                v[0] = lo.x; v[1] = lo.y; v[2] = lo.z; v[3] = lo.w;
                v[4] = hi.x; v[5] = hi.y; v[6] = hi.z; v[7] = hi.w;
                int e0 = sm->rs[wave][rowl], e1 = sm->rs[wave][rowl + 1];
                for (int e = e0; e < e1; ++e) {
                    int sr = sm->ci[wave][e];
                    float4 l2 = *(const float4*)&xw[sr * 16 + quad * 8];
                    float4 h2 = *(const float4*)&xw[sr * 16 + quad * 8 + 4];
                    v[0] += l2.x; v[1] += l2.y; v[2] += l2.z; v[3] += l2.w;
                    v[4] += h2.x; v[5] += h2.y; v[6] += h2.z; v[7] += h2.w;
                }
            }
            af[mt] = quant8(v);
        }
        #pragma unroll
        for (int nt = 0; nt < 8; ++nt) {
            bf16x8 b;
            if (quad < 2) b = *(const bf16x8*)(const void*)&w11l[(nt * 16 + l16) * 16 + quad * 8];
            else { float z[8] = {0,0,0,0,0,0,0,0}; b = quant8(z); }
            acc[0][nt] = __builtin_amdgcn_mfma_f32_16x16x32_bf16(af[0], b, acc[0][nt], 0, 0, 0);
            acc[1][nt] = __builtin_amdgcn_mfma_f32_16x16x32_bf16(af[1], b, acc[1][nt], 0, 0, 0);
        }
    }

    float ls[8], lq[8];
    unsigned short* ub = uout + (size_t)(g0 + wave) * 32 * 128;
    #pragma unroll
    for (int nt = 0; nt < 8; ++nt) {
        int col = nt * 16 + l16;
        float bv = b11[col];
        float s0 = 0.f, q0 = 0.f;
        #pragma unroll
        for (int mt = 0; mt < 2; ++mt) {
            int rb = mt * 16 + quad * 4;
            #pragma unroll
            for (int r = 0; r < 4; ++r) {
                float u = acc[mt][nt][r] + bv;
                ub[(size_t)(rb + r) * 128 + col] = f2bf(u);
                s0 += u; q0 += u * u;
            }
        }
        ls[nt] = s0; lq[nt] = q0;
    }
    __syncthreads();
    #pragma unroll
    for (int nt = 0; nt < 8; ++nt) {
        float s = ls[nt], q = lq[nt];
        s += __shfl_xor(s, 16); q += __shfl_xor(q, 16);
        s += __shfl_xor(s, 32); q += __shfl_xor(q, 32);
        if (quad == 0) {
            int col = nt * 16 + l16;
            red[(wave * 2 + 0) * 128 + col] = s;
            red[(wave * 2 + 1) * 128 + col] = q;
        }
    }
    __syncthreads();
    if (tid < 128) {
        float s = red[0 * 128 + tid] + red[2 * 128 + tid] + red[4 * 128 + tid] + red[6 * 128 + tid];
        float q = red[1 * 128 + tid] + red[3 * 128 + tid] + red[5 * 128 + tid] + red[7 * 128 + tid];
        part[(size_t)bid * 256 + tid] = s;
        part[(size_t)bid * 256 + 128 + tid] = q;
    }
}

// ---------------------------------------------------------------------------
// gin_s3f body (fused GEMM+aggregation, W LDS tile, zt overlay)
// ---------------------------------------------------------------------------
struct S3fSmem {
    unsigned short wsl[128 * 136];
    float pmv[256];
    int rs[2][33];
    int ci[2][64];
};

__device__ void dev_gin_s3f(S3fSmem* sm, int bid,
                            const unsigned short* __restrict__ uin,
                            const int* __restrict__ row_start,
                            const int* __restrict__ col_idx,
                            const unsigned short* __restrict__ Wt,
                            const float* __restrict__ bias,
                            const float* __restrict__ in_stats, float inv_sM,
                            unsigned short* __restrict__ uout,
                            float* __restrict__ part)
{
    float* zt = (float*)sm->wsl;   // 64*132 floats overlay W tile

    int tid  = threadIdx.x;
    int wave = tid >> 6;
    int lane = tid & 63;
    int quad = lane >> 4;
    int l16  = lane & 15;
    int g0   = bid * 2;
    int row0 = bid * 64;

    if (tid < 128) {
        float s = in_stats[tid], ss = in_stats[128 + tid];
        float mn = s * inv_sM;
        sm->pmv[tid] = mn;
        sm->pmv[128 + tid] = rsqrtf(ss * inv_sM - mn * mn + BN_EPS);
    }
    if (tid < 66) {
        int gl = tid / 33, idx = tid - gl * 33;
        sm->rs[gl][idx] = row_start[(g0 + gl) * 33 + idx];
    }
    if (tid >= 128) {
        int t = tid - 128;
        sm->ci[t >> 6][t & 63] = col_idx[(g0 + (t >> 6)) * EPG + (t & 63)];
    }
    for (int i = tid; i < 128 * 32; i += 256) {
        int n = i >> 5, k = (i & 31) * 4;
        *(us4*)&sm->wsl[n * 136 + k] = *(const us4*)&Wt[(size_t)n * 128 + k];
    }
    __syncthreads();

    bf16x8 afrag[4];
    {
        const unsigned short* ap = uin + (size_t)(row0 + wave * 16 + l16) * 128;
        #pragma unroll
        for (int ks = 0; ks < 4; ++ks) {
            int kb = ks * 32 + quad * 8;
            float v[8];
            bf2f8(*(const bf16x8*)(const void*)&ap[kb], v);
            #pragma unroll
            for (int j = 0; j < 8; ++j)
                v[j] = (fmaxf(v[j], 0.f) - sm->pmv[kb + j]) * sm->pmv[128 + kb + j];
            afrag[ks] = quant8(v);
        }
    }

    f32x4 acc[8];
    #pragma unroll
    for (int j = 0; j < 8; ++j) acc[j] = (f32x4){0.f, 0.f, 0.f, 0.f};
    #pragma unroll
    for (int ks = 0; ks < 4; ++ks) {
        int kb = ks * 32 + quad * 8;
        #pragma unroll
        for (int nt = 0; nt < 8; ++nt) {
            bf16x8 b = *(const bf16x8*)(const void*)&sm->wsl[(nt * 16 + l16) * 136 + kb];
            acc[nt] = __builtin_amdgcn_mfma_f32_16x16x32_bf16(afrag[ks], b, acc[nt], 0, 0, 0);
        }
    }
    __syncthreads();   // ALL waves done reading W -> overlay safe

    #pragma unroll
    for (int nt = 0; nt < 8; ++nt) {
        int col = nt * 16 + l16;
        #pragma unroll
        for (int r = 0; r < 4; ++r)
            zt[(wave * 16 + quad * 4 + r) * 132 + col] = acc[nt][r];
    }
    __syncthreads();

    float sv[4] = {0.f, 0.f, 0.f, 0.f}, qv[4] = {0.f, 0.f, 0.f, 0.f};
    {
        int c4  = (tid & 31) * 4;
        int rg  = tid >> 5;
        int hh  = rg >> 2;
        int rb0 = (rg & 3) * 8;
        float4 bv = *(const float4*)&bias[c4];
        unsigned short* ub = uout + (size_t)row0 * 128;
        for (int rr = 0; rr < 8; ++rr) {
            int r = rb0 + rr;
            int lr = hh * 32 + r;
            float4 val = *(const float4*)&zt[lr * 132 + c4];
            int e0 = sm->rs[hh][r], e1 = sm->rs[hh][r + 1];
            for (int e = e0; e < e1; ++e) {
                float4 zz = *(const float4*)&zt[(hh * 32 + sm->ci[hh][e]) * 132 + c4];
                val.x += zz.x; val.y += zz.y; val.z += zz.z; val.w += zz.w;
            }
            float u0 = val.x + bv.x, u1 = val.y + bv.y;
            float u2 = val.z + bv.z, u3 = val.w + bv.w;
            *(us4*)&ub[(size_t)lr * 128 + c4] =
                (us4){ f2bf(u0), f2bf(u1), f2bf(u2), f2bf(u3) };
            sv[0] += u0; sv[1] += u1; sv[2] += u2; sv[3] += u3;
            qv[0] += u0 * u0; qv[1] += u1 * u1; qv[2] += u2 * u2; qv[3] += u3 * u3;
        }
    }
    __syncthreads();
    {
        int c4 = (tid & 31) * 4, rg = tid >> 5;
        #pragma unroll
        for (int j = 0; j < 4; ++j) {
            zt[rg * 128 + c4 + j] = sv[j];
            zt[1024 + rg * 128 + c4 + j] = qv[j];
        }
    }
    __syncthreads();
    if (tid < 128) {
        float s = 0.f, q = 0.f;
        #pragma unroll
        for (int rg = 0; rg < 8; ++rg) {
            s += zt[rg * 128 + tid];
            q += zt[1024 + rg * 128 + tid];
        }
        part[(size_t)bid * 256 + tid] = s;
        part[(size_t)bid * 256 + 128 + tid] = q;
    }
}

// ---------------------------------------------------------------------------
// gin_lin body (streaming GEMM, W LDS tile)
// ---------------------------------------------------------------------------
struct LinSmem {
    unsigned short Ws_l[128 * 136];
    float pmv[256];
    float red[4][2][128];
};

template<int DO_POOL>
__device__ void dev_gin_lin(LinSmem* sm, int bid,
                            const unsigned short* __restrict__ uin,
                            const unsigned short* __restrict__ Wt,
                            const float* __restrict__ bias,
                            const float* __restrict__ in_stats, float inv_sM,
                            unsigned short* uout,
                            float* __restrict__ part,
                            float* __restrict__ pool_out)
{
    int tid  = threadIdx.x;
    int wave = tid >> 6;
    int lane = tid & 63;
    int quad = lane >> 4;
    int l16  = lane & 15;
    int row0 = bid * 64;

    for (int i = tid; i < 128 * 32; i += 256) {
        int n = i >> 5, k = (i & 31) * 4;
        *(us4*)&sm->Ws_l[n * 136 + k] = *(const us4*)&Wt[(size_t)n * 128 + k];
    }
    if (tid < 128) {
        float s = in_stats[tid], ss = in_stats[128 + tid];
        float mn = s * inv_sM;
        sm->pmv[tid] = mn;
        sm->pmv[128 + tid] = rsqrtf(ss * inv_sM - mn * mn + BN_EPS);
    }
    __syncthreads();

    bf16x8 afrag[4];
    {
        const unsigned short* ap = uin + (size_t)(row0 + wave * 16 + l16) * 128;
        #pragma unroll
        for (int ks = 0; ks < 4; ++ks) {
            int kb = ks * 32 + quad * 8;
            float v[8];
            bf2f8(*(const bf16x8*)(const void*)&ap[kb], v);
            #pragma unroll
            for (int j = 0; j < 8; ++j)
                v[j] = fmaxf((v[j] - sm->pmv[kb + j]) * sm->pmv[128 + kb + j], 0.f);
            afrag[ks] = quant8(v);
        }
    }

    f32x4 acc[8];
    #pragma unroll
    for (int j = 0; j < 8; ++j) acc[j] = (f32x4){0.f, 0.f, 0.f, 0.f};
    #pragma unroll
    for (int ks = 0; ks < 4; ++ks) {
        int kb = ks * 32 + quad * 8;
        #pragma unroll
        for (int nt = 0; nt < 8; ++nt) {
            bf16x8 b = *(const bf16x8*)(const void*)&sm->Ws_l[(nt * 16 + l16) * 136 + kb];
            acc[nt] = __builtin_amdgcn_mfma_f32_16x16x32_bf16(afrag[ks], b, acc[nt], 0, 0, 0);
        }
    }

    float ls[8], lq[8], lm[8];
    #pragma unroll
    for (int nt = 0; nt < 8; ++nt) {
        int col = nt * 16 + l16;
        float bv = bias[col];
        int rb = row0 + wave * 16 + quad * 4;
        float s0 = 0.f, q0 = 0.f, mx = -INFINITY;
        #pragma unroll
        for (int r = 0; r < 4; ++r) {
            float u = acc[nt][r] + bv;
            float ru = fmaxf(u, 0.f);
            s0 += ru; q0 += ru * ru;
            if (DO_POOL) mx = fmaxf(mx, ru);
            else uout[(size_t)(rb + r) * 128 + col] = f2bf(u);
        }
        ls[nt] = s0; lq[nt] = q0; lm[nt] = mx;
    }

    #pragma unroll
    for (int nt = 0; nt < 8; ++nt) {
        float s = ls[nt], q = lq[nt];
        s += __shfl_xor(s, 16); q += __shfl_xor(q, 16);
        s += __shfl_xor(s, 32); q += __shfl_xor(q, 32);
        if (quad == 0) {
            sm->red[wave][0][nt * 16 + l16] = s;
            sm->red[wave][1][nt * 16 + l16] = q;
        }
    }
    __syncthreads();
    if (tid < 128) {
        float s = sm->red[0][0][tid] + sm->red[1][0][tid] + sm->red[2][0][tid] + sm->red[3][0][tid];
        float q = sm->red[0][1][tid] + sm->red[1][1][tid] + sm->red[2][1][tid] + sm->red[3][1][tid];
        part[(size_t)bid * 256 + tid] = s;
        part[(size_t)bid * 256 + 128 + tid] = q;
    }
    if (DO_POOL) {
        __syncthreads();
        #pragma unroll
        for (int nt = 0; nt < 8; ++nt) {
            float m = lm[nt];
            m = fmaxf(m, __shfl_xor(m, 16));
            m = fmaxf(m, __shfl_xor(m, 32));
            if (quad == 0) sm->red[wave][0][nt * 16 + l16] = m;
        }
        __syncthreads();
        {
            int gi = tid >> 7, col = tid & 127;
            float m = fmaxf(sm->red[gi * 2][0][col], sm->red[gi * 2 + 1][0][col]);
            pool_out[(size_t)((row0 >> 5) + gi) * 128 + col] = m;
        }
    }
}

// ---------------------------------------------------------------------------
// gemm_rB body (16-row blocks, W direct from L2)
// ---------------------------------------------------------------------------
struct RBSmem { float pm[256]; float pv[256]; };

template<int KSTEPS, int NT>
__device__ void dev_rB(RBSmem* sm, int bid,
                       const float* __restrict__ A, const float* __restrict__ A2,
                       int lda, int K, int stats_K, int ksplit,
                       const unsigned short* __restrict__ Wt,
                       const float* __restrict__ bias, float* __restrict__ C,
                       const float* __restrict__ in_stats, float inv_sM, int in_mode,
                       float* __restrict__ part, int stats_mode, int out_act)
{
    constexpr int NSUBW = NT / 64;
    int tid  = threadIdx.x;
    int wave = tid >> 6;
    int lane = tid & 63;
    int quad = lane >> 4;
    int l16  = lane & 15;
    int m0   = bid * 16;

    if (in_mode) {
        for (int k = tid; k < KSTEPS * 32; k += 256) {
            float mn = 0.f, iv = 1.f;
            if (k < stats_K) {
                float s = in_stats[k], ss = in_stats[stats_K + k];
                mn = s * inv_sM;
                float vr = ss * inv_sM - mn * mn;
                iv = rsqrtf(vr + BN_EPS);
            }
            sm->pm[k] = mn; sm->pv[k] = iv;
        }
        __syncthreads();
    }

    bf16x8 afrag[KSTEPS];
    {
        int row = m0 + l16;
        const float* ap = A + (size_t)row * lda;
        #pragma unroll
        for (int ks = 0; ks < KSTEPS; ++ks) {
            int kb = ks * 32 + quad * 8;
            float v[8];
            #pragma unroll
            for (int hh = 0; hh < 2; ++hh) {
                int k = kb + hh * 4;
                const float* p = (k >= ksplit) ? &A2[(size_t)row * 128 + (k - 128)]
                                               : &ap[k];
                float4 f = *(const float4*)p;
                v[hh * 4 + 0] = f.x; v[hh * 4 + 1] = f.y;
                v[hh * 4 + 2] = f.z; v[hh * 4 + 3] = f.w;
            }
            if (in_mode) {
                #pragma unroll
                for (int j = 0; j < 8; ++j)
                    v[j] = apply_in(v[j], in_mode, sm->pm[kb + j], sm->pv[kb + j]);
            }
            afrag[ks] = quant8(v);
        }
    }

    f32x4 acc[NSUBW];
    #pragma unroll
    for (int j = 0; j < NSUBW; ++j) acc[j] = (f32x4){0.f, 0.f, 0.f, 0.f};

    #pragma unroll
    for (int ks = 0; ks < KSTEPS; ++ks) {
        #pragma unroll
        for (int nt = 0; nt < NSUBW; ++nt) {
            int wrow = (wave * NSUBW + nt) * 16 + l16;
            bf16x8 b = *(const bf16x8*)(const void*)&Wt[(size_t)wrow * K + ks * 32 + quad * 8];
            acc[nt] = __builtin_amdgcn_mfma_f32_16x16x32_bf16(afrag[ks], b, acc[nt], 0, 0, 0);
        }
    }

    float ls[NSUBW], lq[NSUBW];
    #pragma unroll
    for (int nt = 0; nt < NSUBW; ++nt) { ls[nt] = 0.f; lq[nt] = 0.f; }

    #pragma unroll
    for (int nt = 0; nt < NSUBW; ++nt) {
        int col = (wave * NSUBW + nt) * 16 + l16;
        float bv = bias[col];
        int rbase = m0 + quad * 4;
        #pragma unroll
        for (int r = 0; r < 4; ++r) {
            float u = acc[nt][r] + bv;
            if (C) {
                float wv = out_act ? fmaxf(u, 0.f) : u;
                C[(size_t)(rbase + r) * NT + col] = wv;
            }
            if (stats_mode) {
                float s = (stats_mode == 2) ? fmaxf(u, 0.f) : u;
                ls[nt] += s; lq[nt] += s * s;
            }
        }
    }

    if (stats_mode) {
        #pragma unroll
        for (int nt = 0; nt < NSUBW; ++nt) {
            float s = ls[nt], q = lq[nt];
            s += __shfl_xor(s, 16); q += __shfl_xor(q, 16);
            s += __shfl_xor(s, 32); q += __shfl_xor(q, 32);
            if (quad == 0) {
                int col = (wave * NSUBW + nt) * 16 + l16;
                part[(size_t)bid * 256 + col] = s;
                part[(size_t)bid * 256 + 128 + col] = q;
            }
        }
    }
}

// ---------------------------------------------------------------------------
// gemm_cell body (software-pipelined, K-chunk 128, tile 32 x NT), flattened:
// bid -> m0 = (bid & 255)*32, n-block = bid >> 8.
// ---------------------------------------------------------------------------
template<int NT>
struct CellSmem {
    unsigned short As_l[32 * 136];
    unsigned short Ws_l[NT * 136];
    float red[2][2][NT];
};

template<int NT>
__device__ void dev_gemm_cell(CellSmem<NT>* sm, int bid,
                              const unsigned short* __restrict__ Abf, int abf_str,
                              const unsigned short* __restrict__ Wt,
                              const float* __restrict__ bias, float* __restrict__ C,
                              int K, int N, float* __restrict__ out_stats)
{
    constexpr int NSUB = NT / 32;
    constexpr int WITEMS = NT * 32 / 256;
    int tid = threadIdx.x;
    int wave = tid >> 6;
    int lane = tid & 63;
    int quad = lane >> 4;
    int l16 = lane & 15;
    int mhalf = wave & 1, nhalf = wave >> 1;
    int m0 = (bid & 255) * 32, n0 = (bid >> 8) * NT;

    us8 aReg[2];
    us4 wReg[WITEMS];

    auto loadA = [&](int k0) {
        #pragma unroll
        for (int t = 0; t < 2; ++t) {
            int i = t * 256 + tid;
            int row = i >> 4, c8 = (i & 15) * 8;
            aReg[t] = *(const us8*)&Abf[(size_t)(m0 + row) * abf_str + k0 + c8];
        }
    };
    auto loadW = [&](int k0) {
        #pragma unroll
        for (int t = 0; t < WITEMS; ++t) {
            int i = t * 256 + tid;
            int nn = i >> 5, kt = i & 31;
            int k = k0 + kt * 4;
            int gn = n0 + nn;
            us4 w4 = (us4){0, 0, 0, 0};
            if (gn < N && k < K) w4 = *(const us4*)&Wt[(size_t)gn * K + k];
            wReg[t] = w4;
        }
    };
    auto storeAW = [&]() {
        #pragma unroll
        for (int t = 0; t < 2; ++t) {
            int i = t * 256 + tid;
            int row = i >> 4, c8 = (i & 15) * 8;
            *(us8*)&sm->As_l[row * 136 + c8] = aReg[t];
        }
        #pragma unroll
        for (int t = 0; t < WITEMS; ++t) {
            int i = t * 256 + tid;
            int nn = i >> 5, kt = i & 31;
            *(us4*)&sm->Ws_l[nn * 136 + kt * 4] = wReg[t];
        }
    };

    f32x4 acc[NSUB];
    #pragma unroll
    for (int j = 0; j < NSUB; ++j) acc[j] = (f32x4){0.f, 0.f, 0.f, 0.f};

    int nch = (K + 127) >> 7;
    loadA(0); loadW(0);
    for (int c = 0; c < nch; ++c) {
        storeAW();
        if (c + 1 < nch) { loadA((c + 1) * 128); loadW((c + 1) * 128); }
        __syncthreads();
        #pragma unroll
        for (int ks = 0; ks < 4; ++ks) {
            bf16x8 a = *(const bf16x8*)(const void*)
                &sm->As_l[(mhalf * 16 + l16) * 136 + ks * 32 + quad * 8];
            #pragma unroll
            for (int nt = 0; nt < NSUB; ++nt) {
                bf16x8 b = *(const bf16x8*)(const void*)
                    &sm->Ws_l[(nhalf * (NT / 2) + nt * 16 + l16) * 136 + ks * 32 + quad * 8];
                acc[nt] = __builtin_amdgcn_mfma_f32_16x16x32_bf16(a, b, acc[nt], 0, 0, 0);
            }
        }
        __syncthreads();
    }

    float ls[NSUB], lq[NSUB];
    #pragma unroll
    for (int nt = 0; nt < NSUB; ++nt) { ls[nt] = 0.f; lq[nt] = 0.f; }

    #pragma unroll
    for (int nt = 0; nt < NSUB; ++nt) {
        int col = n0 + nhalf * (NT / 2) + nt * 16 + l16;
        if (col < N) {
            float bv = bias[col];
            int rbase = m0 + mhalf * 16 + quad * 4;
            #pragma unroll
            for (int r = 0; r < 4; ++r) {
                float u = acc[nt][r] + bv;
                C[(size_t)(rbase + r) * N + col] = u;
                ls[nt] += u; lq[nt] += u * u;
            }
        }
    }

    #pragma unroll
    for (int nt = 0; nt < NSUB; ++nt) {
        float s = ls[nt], q = lq[nt];
        s += __shfl_xor(s, 16); q += __shfl_xor(q, 16);
        s += __shfl_xor(s, 32); q += __shfl_xor(q, 32);
        if (quad == 0) {
            int lc = nhalf * (NT / 2) + nt * 16 + l16;
            sm->red[mhalf][0][lc] = s;
            sm->red[mhalf][1][lc] = q;
        }
    }
    __syncthreads();
    if (tid < NT) {
        int col = n0 + tid;
        if (col < N) {
            float s = sm->red[0][0][tid] + sm->red[1][0][tid];
            float q = sm->red[0][1][tid] + sm->red[1][1][tid];
            unsafeAtomicAdd(&out_stats[col], s);
            unsafeAtomicAdd(&out_stats[N + col], q);
        }
    }
}

// ===========================================================================
// Fused kernels (block-range dispatch; LDS = union of branch needs)
// ===========================================================================
__global__ __launch_bounds__(256)
void prep(TransArgs ta, SetupArgs sa, const float* cell, unsigned short* abf,
          int nbT, int nbZC)
{
    __shared__ __align__(16) char smem[sizeof(TransSmem)];
    int b = blockIdx.x;
    if (b < nbT) { dev_transpose((TransSmem*)smem, b, ta); return; }
    b -= nbT;
    if (b < nbZC) { dev_setup((SetupSmem*)smem, b, sa); return; }
    b -= nbZC;
    dev_quant_cell(b, cell, abf);
}

__global__ __launch_bounds__(256)
void f_s1_ce1(const float* drug_x, const int* row_start, const int* col_idx,
              const unsigned short* W11, const float* b11,
              unsigned short* uout, float* partA,
              const unsigned short* Abf, const unsigned short* Wt0,
              const float* ce1b, float* c1, float* st_c1, int nb1)
{
    constexpr size_t SZ = sizeof(S1Smem) > sizeof(CellSmem<128>)
                        ? sizeof(S1Smem) : sizeof(CellSmem<128>);
    __shared__ __align__(16) char smem[SZ];
    int b = blockIdx.x;
    if (b < nb1)
        dev_gin_s1((S1Smem*)smem, b, drug_x, row_start, col_idx, W11, b11, uout, partA);
    else
        dev_gemm_cell<128>((CellSmem<128>*)smem, b - nb1, Abf, ABF_STR, Wt0,
                           ce1b, c1, CELLD, 516, st_c1);
}

__global__ __launch_bounds__(256)
void f_red_qc1(const float* partA, int nrows, float* out,
               const float* c1, const float* st_c1, float inv_B,
               unsigned short* c1bf, int nb1)
{
    int b = blockIdx.x;
    if (b < nb1) dev_reduce(b, partA, nrows, 128, out);
    else dev_quant_c1(b - nb1, c1, st_c1, inv_B, c1bf);
}

__global__ __launch_bounds__(256)
void f_lin0_ce2(const unsigned short* uin, const unsigned short* Wt4,
                const float* g12b, const float* st_u1, float inv_N,
                unsigned short* uout, float* partA,
                const unsigned short* C1bf, const unsigned short* Wt1,
                const float* ce2b, float* c2, float* st_c2, int nb1)
{
    constexpr size_t SZ = sizeof(LinSmem) > sizeof(CellSmem<64>)
                        ? sizeof(LinSmem) : sizeof(CellSmem<64>);
    __shared__ __align__(16) char smem[SZ];
    int b = blockIdx.x;
    if (b < nb1)
        dev_gin_lin<0>((LinSmem*)smem, b, uin, Wt4, g12b, st_u1, inv_N,
                       uout, partA, nullptr);
    else
        dev_gemm_cell<64>((CellSmem<64>*)smem, b - nb1, C1bf, C1_STR, Wt1,
                          ce2b, c2, 516, 256, st_c2);
}

__global__ __launch_bounds__(256)
void f_red_ce3(const float* partA, int nrows, float* out,
               const float* c2, const unsigned short* Wt2, const float* ce3b,
               float* c3u, const float* st_c2, float inv_B, float* partB, int nb1)
{
    __shared__ __align__(16) char smem[sizeof(RBSmem)];
    int b = blockIdx.x;
    if (b < nb1) dev_reduce(b, partA, nrows, 128, out);
    else dev_rB<8, 128>((RBSmem*)smem, b - nb1, c2, nullptr, 256, 256, 256,
                        1 << 30, Wt2, ce3b, c3u, st_c2, inv_B, 1, partB, 1, 0);
}

__global__ __launch_bounds__(256)
void f_s3f_red(const unsigned short* uin, const int* row_start, const int* col_idx,
               const unsigned short* Wt5, const float* g21b,
               const float* st_u2rel, float inv_N, unsigned short* uout,
               float* partA, const float* partB, int nrowsB, float* st_c3, int nb1)
{
    __shared__ __align__(16) char smem[sizeof(S3fSmem)];
    int b = blockIdx.x;
    if (b < nb1)
        dev_gin_s3f((S3fSmem*)smem, b, uin, row_start, col_idx, Wt5, g21b,
                    st_u2rel, inv_N, uout, partA);
    else
        dev_reduce(b - nb1, partB, nrowsB, 128, st_c3);
}

// ===========================================================================
// Standalone kernels
// ===========================================================================
__global__ __launch_bounds__(256)
void reduce_stats(const float* __restrict__ part, int nrows, int nt,
                  float* __restrict__ out)
{
    dev_reduce(blockIdx.x, part, nrows, nt, out);
}

__global__ __launch_bounds__(256)
void gin_lin1(const unsigned short* uin, const unsigned short* Wt,
              const float* bias, const float* in_stats, float inv_sM,
              float* part, float* pool_out)
{
    __shared__ __align__(16) char smem[sizeof(LinSmem)];
    dev_gin_lin<1>((LinSmem*)smem, blockIdx.x, uin, Wt, bias, in_stats, inv_sM,
                   nullptr, part, pool_out);
}

template<int KSTEPS, int NT>
__global__ __launch_bounds__(256)
void gemm_rB(const float* A, const float* A2, int lda, int K, int stats_K,
             int ksplit, const unsigned short* Wt, const float* bias, float* C,
             const float* in_stats, float inv_sM, int in_mode,
             float* part, int stats_mode, int out_act)
{
    __shared__ __align__(16) char smem[sizeof(RBSmem)];
    dev_rB<KSTEPS, NT>((RBSmem*)smem, blockIdx.x, A, A2, lda, K, stats_K, ksplit,
                       Wt, bias, C, in_stats, inv_sM, in_mode, part, stats_mode, out_act);
}

__global__ void final_dot(const float* __restrict__ u, const float* __restrict__ w,
                          const float* __restrict__ b, float* __restrict__ y,
                          const float* __restrict__ stats, float inv_sM)
{
    __shared__ float pmv[64], piv[64], sw[64];
    int tid = threadIdx.x;
    if (tid < 64) {
        float s = stats[tid], ss = stats[64 + tid];
        float mn = s * inv_sM;
        float vr = ss * inv_sM - mn * mn;
        pmv[tid] = mn;
        piv[tid] = rsqrtf(vr + BN_EPS);
        sw[tid] = w[tid];
    }
    __syncthreads();
    int i = blockIdx.x * blockDim.x + tid;
    if (i >= BGRAPH) return;
    float acc = 0.f;
    #pragma unroll
    for (int k = 0; k < 64; ++k) {
        float v = (u[(size_t)i * 64 + k] - pmv[k]) * piv[k];
        v = (v > 0.f) ? v : expm1f(v);
        acc += v * sw[k];
    }
    y[i] = acc + b[0];
}

// ---------------------------------------------------------------------------
// Host driver. 17 launches; cell chain overlapped with GIN chain via fusion.
// ---------------------------------------------------------------------------
extern "C" void kernel_launch(void* const* d_in, const int* in_sizes, int n_in,
                              void* d_out, int out_size, void* d_ws, size_t ws_size,
                              hipStream_t stream)
{
    const float* cell   = (const float*)d_in[0];
    const float* drug_x = (const float*)d_in[1];
    const int*   eidx   = (const int*)d_in[2];
    const float* ce1w = (const float*)d_in[4];  const float* ce1b = (const float*)d_in[5];
    const float* ce2w = (const float*)d_in[6];  const float* ce2b = (const float*)d_in[7];
    const float* ce3w = (const float*)d_in[8];  const float* ce3b = (const float*)d_in[9];
    const float* g11w = (const float*)d_in[10]; const float* g11b = (const float*)d_in[11];
    const float* g12w = (const float*)d_in[12]; const float* g12b = (const float*)d_in[13];
    const float* g21w = (const float*)d_in[14]; const float* g21b = (const float*)d_in[15];
    const float* g22w = (const float*)d_in[16]; const float* g22b = (const float*)d_in[17];
    const float* d1w  = (const float*)d_in[18]; const float* d1b  = (const float*)d_in[19];
    const float* d2w  = (const float*)d_in[20]; const float* d2b  = (const float*)d_in[21];
    const float* f1w  = (const float*)d_in[22]; const float* f1b  = (const float*)d_in[23];
    const float* f2w  = (const float*)d_in[24]; const float* f2b  = (const float*)d_in[25];
    const float* f3w  = (const float*)d_in[26]; const float* f3b  = (const float*)d_in[27];

    const int* src = eidx;
    const int* dst = eidx + NEDGE;
    float* out = (float*)d_out;

    const float INV_N = 1.f / (float)NNODE;
    const float INV_B = 1.f / (float)BGRAPH;
    const int KBIG = 1 << 30;

    // ---- workspace layout ----
    // ubg (64MB) live through GIN chain; d/head fp32 buffers alias it (dead
    // after lin1). Cell branch OVERLAPS the GIN chain, so c1/c2/c3u get a
    // FRESH region (c2/c3u overlay c1's space only after c1 is dead).
    float* ws = (float*)d_ws;
    unsigned short* ubg = (unsigned short*)ws;            // NNODE*128 ushorts
    float* pbuf = ws + (size_t)NNODE * 64;                // BGRAPH*128 floats
    float* sb   = pbuf + (size_t)BGRAPH * 128;            // 10*1032 stats floats
    unsigned short* wtb = (unsigned short*)(sb + 10 * 1032);
    auto ST = [&](int i) { return sb + (size_t)i * 1032; };
    float* st_u1    = ST(0);
    float* st_u2rel = ST(1);
    float* st_u3    = ST(2);
    float* st_u4rel = ST(3);
    float* st_c1    = ST(4);
    float* st_c2    = ST(5);
    float* st_c3    = ST(6);
    float* st_d1    = ST(7);
    float* st_f1    = ST(8);
    float* st_f2    = ST(9);

    struct WDef { const float* w; int K; int N; };
    WDef wd[11] = {
        {ce1w, CELLD, 516}, {ce2w, 516, 256}, {ce3w, 256, 128},
        {g11w, 9, 128}, {g12w, 128, 128}, {g21w, 128, 128}, {g22w, 128, 128},
        {d1w, 128, 128}, {d2w, 128, 128}, {f1w, 256, 128}, {f2w, 128, 64}
    };
    TransArgs ta;
    int off = 0;
    unsigned short* wt[11];
    ta.off[0] = 0;
    for (int i = 0; i < 11; ++i) {
        wt[i] = wtb + off;
        ta.w[i] = wd[i].w; ta.wt[i] = wt[i];
        ta.K[i] = wd[i].K; ta.N[i] = wd[i].N;
        ta.ntN[i] = (wd[i].N + 63) / 64;
        ta.off[i + 1] = ta.off[i] + ((wd[i].K + 63) / 64) * ta.ntN[i];
        off += wd[i].K * wd[i].N;
    }

    SetupArgs sa;
    sa.zb = sb; sa.zTotal = 10 * 1032; sa.zBlocks = (10 * 1032 + 255) / 256;
    sa.src = src; sa.dst = dst;

    int csr_off = (off + 7) & ~7;
    int* row_start = (int*)(wtb + csr_off);
    int* col_idx   = row_start + (size_t)BGRAPH * 33;
    float* partA = (float*)(col_idx + (size_t)NEDGE);      // 4096*256 floats
    float* partB = partA + (size_t)4096 * 256;             // 512*256 floats
    unsigned short* Abf  = (unsigned short*)(partB + (size_t)512 * 256);
    unsigned short* C1bf = Abf + (size_t)BGRAPH * ABF_STR;
    // fresh fp32 cell region (c1 dead after quant_c1; c2/c3u overlay it)
    float* cellws = (float*)(C1bf + (size_t)BGRAPH * C1_STR);  // 8192*516 floats
    float* c1  = cellws;
    float* c2  = cellws;                                   // written after c1 dead
    float* c3u = cellws + (size_t)BGRAPH * 256;            // disjoint from c2
    // d/head buffers alias ubg (dead by the time these run)
    float* dbuf  = ws;
    float* d2buf = dbuf + (size_t)BGRAPH * 128;
    float* f1o   = d2buf + (size_t)BGRAPH * 128;
    float* f2o   = f1o + (size_t)BGRAPH * 128;
    sa.row_start = row_start; sa.col_idx = col_idx;

    int nbT = ta.off[11];
    int nbZC = sa.zBlocks + BGRAPH / 4;

    // L0: transpose + zero + CSR + quant_cell (all independent)
    prep<<<nbT + nbZC + 8192, 256, 0, stream>>>(ta, sa, cell, Abf, nbT, nbZC);

    // L1: gin_s1 (2048) + ce1 (1280)
    f_s1_ce1<<<2048 + 1280, 256, 0, stream>>>(
        drug_x, row_start, col_idx, wt[3], g11b, ubg, partA,
        Abf, wt[0], ce1b, c1, st_c1, 2048);

    // L2: reduce u1 (64) + quant_c1 (5120)
    f_red_qc1<<<64 + 5120, 256, 0, stream>>>(
        partA, BGRAPH / 4, st_u1, c1, st_c1, INV_B, C1bf, 64);

    // L3: gin_lin<0> (4096) + ce2 (1024)
    f_lin0_ce2<<<4096 + 1024, 256, 0, stream>>>(
        ubg, wt[4], g12b, st_u1, INV_N, ubg, partA,
        C1bf, wt[1], ce2b, c2, st_c2, 4096);

    // L4: reduce u2rel (64) + ce3 (512, writes partB)
    f_red_ce3<<<64 + 512, 256, 0, stream>>>(
        partA, NNODE / 64, st_u2rel, c2, wt[2], ce3b, c3u, st_c2, INV_B, partB, 64);

    // L5: gin_s3f (4096, writes partA) + reduce partB -> st_c3 (64)
    f_s3f_red<<<4096 + 64, 256, 0, stream>>>(
        ubg, row_start, col_idx, wt[5], g21b, st_u2rel, INV_N, ubg, partA,
        partB, BGRAPH / 16, st_c3, 4096);

    reduce_stats<<<64, 256, 0, stream>>>(partA, BGRAPH / 2, 128, st_u3);

    gin_lin1<<<NNODE / 64, 256, 0, stream>>>(
        ubg, wt[6], g22b, st_u3, INV_N, partA, pbuf);
    reduce_stats<<<64, 256, 0, stream>>>(partA, NNODE / 64, 128, st_u4rel);

    // ================= d branch ==============================================
    gemm_rB<4, 128><<<BGRAPH / 16, 256, 0, stream>>>(
        pbuf, nullptr, 128, 128, 128, KBIG, wt[7], d1b, dbuf,
        st_u4rel, INV_N, 3, partA, 1, 0);
    reduce_stats<<<64, 256, 0, stream>>>(partA, BGRAPH / 16, 128, st_d1);
    gemm_rB<4, 128><<<BGRAPH / 16, 256, 0, stream>>>(
        dbuf, nullptr, 128, 128, 128, KBIG, wt[8], d2b, d2buf,
        st_d1, INV_B, 1, partA, 0, 1);

    // ================= head ==================================================
    gemm_rB<8, 128><<<BGRAPH / 16, 256, 0, stream>>>(
        c3u, d2buf, 128, 256, 128, 128, wt[9], f1b, f1o,
        st_c3, INV_B, 1, partA, 1, 0);
    reduce_stats<<<64, 256, 0, stream>>>(partA, BGRAPH / 16, 128, st_f1);
    gemm_rB<4, 64><<<BGRAPH / 16, 256, 0, stream>>>(
        f1o, nullptr, 128, 128, 128, KBIG, wt[10], f2b, f2o,
        st_f1, INV_B, 2, partA, 1, 0);
    reduce_stats<<<64, 256, 0, stream>>>(partA, BGRAPH / 16, 64, st_f2);
    final_dot<<<BGRAPH / 256, 256, 0, stream>>>(f2o, f3w, f3b, out, st_f2, INV_B);
}

// Round 17
// 501.292 us; speedup vs baseline: 1.0682x; 1.0331x over previous
//
#include <hip/hip_runtime.h>
#include <hip/hip_bf16.h>
#include <math.h>

// Problem constants (from reference)
#define BGRAPH 8192
#define NPG 32
#define EPG 64
#define NNODE (BGRAPH * NPG)   // 262144
#define NEDGE (BGRAPH * EPG)   // 524288
#define CELLD 908
#define BN_EPS 1e-5f
#define ABF_STR 1024           // bf16 cell row stride (zero-padded, mult of 128)
#define C1_STR 640             // bf16 c1 row stride (516 padded to mult of 128)

typedef __attribute__((ext_vector_type(8))) short bf16x8;   // 8 bf16 = 4 VGPRs
typedef __attribute__((ext_vector_type(4))) float f32x4;
typedef __attribute__((ext_vector_type(4))) unsigned short us4;
typedef __attribute__((ext_vector_type(8))) unsigned short us8;

__device__ __forceinline__ unsigned short f2bf(float f)
{
    unsigned int u = __float_as_uint(f);
    u = (u + 0x7FFFu + ((u >> 16) & 1u)) >> 16;   // RNE
    return (unsigned short)u;
}

__device__ __forceinline__ bf16x8 quant8(const float v[8])
{
    union { bf16x8 b; unsigned short u[8]; } fr;
    #pragma unroll
    for (int j = 0; j < 8; ++j) fr.u[j] = f2bf(v[j]);
    return fr.b;
}

__device__ __forceinline__ void bf2f8(bf16x8 b, float v[8])
{
    union { bf16x8 bb; unsigned short u[8]; } x; x.bb = b;
    #pragma unroll
    for (int j = 0; j < 8; ++j) v[j] = __uint_as_float((unsigned)x.u[j] << 16);
}

// in_mode: 0=raw, 1=relu((x-m)*iv), 2=elu((x-m)*iv), 3=(relu(x)-m)*iv
__device__ __forceinline__ float apply_in(float v, int mode, float mn, float iv)
{
    if (mode == 1)      { v = (v - mn) * iv; v = fmaxf(v, 0.f); }
    else if (mode == 2) { v = (v - mn) * iv; v = (v > 0.f) ? v : expm1f(v); }
    else if (mode == 3) { v = fmaxf(v, 0.f); v = (v - mn) * iv; }
    return v;
}

// ===========================================================================
// Device bodies (shared-memory passed in so fused kernels can union them)
// ===========================================================================
struct TransArgs {
    const float* w[11];
    unsigned short* wt[11];
    int K[11], N[11], ntN[11];
    int off[12];
};
struct TransSmem { float t[64][65]; };

__device__ void dev_transpose(TransSmem* sm, int b, const TransArgs& a)
{
    int tid = threadIdx.x;
    int s = 0;
    while (s < 10 && b >= a.off[s + 1]) ++s;
    int t0 = b - a.off[s];
    int K = a.K[s], N = a.N[s], ntn = a.ntN[s];
    int kt = t0 / ntn, nt = t0 - kt * ntn;
    int k0 = kt * 64, n0 = nt * 64;
    const float* w = a.w[s];
    unsigned short* wt = a.wt[s];
    int c = tid & 63, rg = tid >> 6;
    #pragma unroll
    for (int i = 0; i < 16; ++i) {
        int rr = rg * 16 + i;
        int k = k0 + rr, n = n0 + c;
        sm->t[c][rr] = (k < K && n < N) ? w[(size_t)k * N + n] : 0.f;
    }
    __syncthreads();
    #pragma unroll
    for (int i = 0; i < 16; ++i) {
        int rr = rg * 16 + i;
        int n = n0 + rr, k = k0 + c;
        if (n < N && k < K) wt[(size_t)n * K + k] = f2bf(sm->t[rr][c]);
    }
}

struct SetupArgs {
    float* zb; int zTotal; int zBlocks;
    const int* src; const int* dst; int* row_start; int* col_idx;
};
struct SetupSmem { int cnt[4][32]; int fill[4][32]; int rsl[4][33]; };

__device__ void dev_setup(SetupSmem* sm, int b, const SetupArgs& a)
{
    int tid = threadIdx.x;
    if (b < a.zBlocks) {
        int i = b * 256 + tid;
        if (i < a.zTotal) a.zb[i] = 0.f;
        return;
    }
    b -= a.zBlocks;
    int gl = tid >> 6, e = tid & 63;
    int g = b * 4 + gl;
    if (e < 32) { sm->cnt[gl][e] = 0; sm->fill[gl][e] = 0; }
    __syncthreads();
    int s = a.src[g * EPG + e] - g * NPG;
    int d = a.dst[g * EPG + e] - g * NPG;
    atomicAdd(&sm->cnt[gl][d], 1);
    __syncthreads();
    if (e == 0) {
        int acc = 0;
        for (int i = 0; i < 32; ++i) { sm->rsl[gl][i] = acc; acc += sm->cnt[gl][i]; }
        sm->rsl[gl][32] = acc;
    }
    __syncthreads();
    int pos = sm->rsl[gl][d] + atomicAdd(&sm->fill[gl][d], 1);
    a.col_idx[g * EPG + pos] = s;
    if (e < 33) a.row_start[g * 33 + e] = sm->rsl[gl][e];
}

__device__ void dev_quant_cell(int bid, const float* __restrict__ cell,
                               unsigned short* __restrict__ abf)
{
    int i = bid * 256 + threadIdx.x;
    int row = i / (ABF_STR / 4), c4 = i - row * (ABF_STR / 4);
    int k = c4 * 4;
    us4 w = (us4){0, 0, 0, 0};
    if (k < CELLD) {
        float4 f = *(const float4*)&cell[(size_t)row * CELLD + k];
        w = (us4){ f2bf(f.x), f2bf(f.y), f2bf(f.z), f2bf(f.w) };
    }
    *(us4*)&abf[(size_t)row * ABF_STR + k] = w;
}

__device__ void dev_quant_c1(int bid, const float* __restrict__ c1,
                             const float* __restrict__ stats, float inv_sM,
                             unsigned short* __restrict__ out)
{
    int i = bid * 256 + threadIdx.x;
    int row = i / (C1_STR / 4), c4 = i - row * (C1_STR / 4);
    int k = c4 * 4;
    us4 w = (us4){0, 0, 0, 0};
    if (k < 516) {
        float4 f = *(const float4*)&c1[(size_t)row * 516 + k];
        float v[4] = {f.x, f.y, f.z, f.w};
        #pragma unroll
        for (int j = 0; j < 4; ++j) {
            float s = stats[k + j], ss = stats[516 + k + j];
            float mn = s * inv_sM;
            float iv = rsqrtf(ss * inv_sM - mn * mn + BN_EPS);
            v[j] = fmaxf((v[j] - mn) * iv, 0.f);
        }
        w = (us4){ f2bf(v[0]), f2bf(v[1]), f2bf(v[2]), f2bf(v[3]) };
    }
    *(us4*)&out[(size_t)row * C1_STR + k] = w;
}

__device__ void dev_reduce(int bid, const float* __restrict__ part, int nrows,
                           int nt, float* __restrict__ out)
{
    int c = threadIdx.x;
    int per = nrows >> 6;
    int r0 = bid * per;
    bool isq = (c >= 128);
    int cc = isq ? c - 128 : c;
    if (cc >= nt) return;
    float s = 0.f;
    for (int r = 0; r < per; ++r) s += part[(size_t)(r0 + r) * 256 + c];
    unsafeAtomicAdd(&out[(isq ? nt : 0) + cc], s);
}

// ---------------------------------------------------------------------------
// gin_s1 body (slim LDS: fp32 32x16 x-tile per wave; verified in r14)
// ---------------------------------------------------------------------------
struct S1Smem {
    float xw[4][32 * 16];
    unsigned char ubuf[4096];
    int rs[4][36];
    int ci[4][64];
};

__device__ void dev_gin_s1(S1Smem* sm, int bid,
                           const float* __restrict__ drug_x,
                           const int* __restrict__ row_start,
                           const int* __restrict__ col_idx,
                           const unsigned short* __restrict__ W11,
                           const float* __restrict__ b11,
                           unsigned short* uout, float* __restrict__ part)
{
    unsigned short* w11l = (unsigned short*)sm->ubuf;
    float* red = (float*)sm->ubuf;

    int tid  = threadIdx.x;
    int wave = tid >> 6;
    int lane = tid & 63;
    int quad = lane >> 4;
    int l16  = lane & 15;
    int g0   = bid * 4;
    float* xw = sm->xw[wave];

    for (int i = tid; i < 128 * 16; i += 256) {
        int n = i >> 4, k = i & 15;
        w11l[i] = (k < 9) ? W11[n * 9 + k] : (unsigned short)0;
    }
    if (tid < 132) {
        int gl = tid / 33, idx = tid - gl * 33;
        sm->rs[gl][idx] = row_start[(g0 + gl) * 33 + idx];
    }
    {
        int gl = tid >> 6, e = tid & 63;
        sm->ci[gl][e] = col_idx[(g0 + gl) * EPG + e];
    }
    {
        const float* xg = drug_x + (size_t)(g0 + wave) * 32 * 9;
        for (int i = lane; i < 32 * 16; i += 64) {
            int rr = i >> 4, c = i & 15;
            xw[i] = (c < 9) ? xg[rr * 9 + c] : 0.f;
        }
    }
    __syncthreads();

    f32x4 acc[2][8];
    #pragma unroll
    for (int i = 0; i < 2; ++i)
        #pragma unroll
        for (int j = 0; j < 8; ++j)
            acc[i][j] = (f32x4){0.f, 0.f, 0.f, 0.f};

    {
        bf16x8 af[2];
        #pragma unroll
        for (int mt = 0; mt < 2; ++mt) {
            int rowl = mt * 16 + l16;
            float v[8] = {0, 0, 0, 0, 0, 0, 0, 0};
            if (quad < 2) {
                float4 lo = *(const float4*)&xw[rowl * 16 + quad * 8];
                float4 hi = *(const float4*)&xw[rowl * 16 + quad * 8 + 4];
                v[0] = lo.x; v[1] = lo.y; v[2] = lo.z; v[3] = lo.w;
                v[4] = hi.x; v[5] = hi.y; v[6] = hi.z; v[7] = hi.w;
                int e0 = sm->rs[wave][rowl], e1 = sm->rs[wave][rowl + 1];
                for (int e = e0; e < e1; ++e) {
                    int sr = sm->ci[wave][e];
                    float4 l2 = *(const float4*)&xw[sr * 16 + quad * 8];
                    float4 h2 = *(const float4*)&xw[sr * 16 + quad * 8 + 4];
                    v[0] += l2.x; v[1] += l2.y; v[2] += l2.z; v[3] += l2.w;
                    v[4] += h2.x; v[5] += h2.y; v[6] += h2.z; v[7] += h2.w;
                }
            }
            af[mt] = quant8(v);
        }
        #pragma unroll
        for (int nt = 0; nt < 8; ++nt) {
            bf16x8 b;
            if (quad < 2) b = *(const bf16x8*)(const void*)&w11l[(nt * 16 + l16) * 16 + quad * 8];
            else { float z[8] = {0,0,0,0,0,0,0,0}; b = quant8(z); }
            acc[0][nt] = __builtin_amdgcn_mfma_f32_16x16x32_bf16(af[0], b, acc[0][nt], 0, 0, 0);
            acc[1][nt] = __builtin_amdgcn_mfma_f32_16x16x32_bf16(af[1], b, acc[1][nt], 0, 0, 0);
        }
    }

    float ls[8], lq[8];
    unsigned short* ub = uout + (size_t)(g0 + wave) * 32 * 128;
    #pragma unroll
    for (int nt = 0; nt < 8; ++nt) {
        int col = nt * 16 + l16;
        float bv = b11[col];
        float s0 = 0.f, q0 = 0.f;
        #pragma unroll
        for (int mt = 0; mt < 2; ++mt) {
            int rb = mt * 16 + quad * 4;
            #pragma unroll
            for (int r = 0; r < 4; ++r) {
                float u = acc[mt][nt][r] + bv;
                ub[(size_t)(rb + r) * 128 + col] = f2bf(u);
                s0 += u; q0 += u * u;
            }
        }
        ls[nt] = s0; lq[nt] = q0;
    }
    __syncthreads();
    #pragma unroll
    for (int nt = 0; nt < 8; ++nt) {
        float s = ls[nt], q = lq[nt];
        s += __shfl_xor(s, 16); q += __shfl_xor(q, 16);
        s += __shfl_xor(s, 32); q += __shfl_xor(q, 32);
        if (quad == 0) {
            int col = nt * 16 + l16;
            red[(wave * 2 + 0) * 128 + col] = s;
            red[(wave * 2 + 1) * 128 + col] = q;
        }
    }
    __syncthreads();
    if (tid < 128) {
        float s = red[0 * 128 + tid] + red[2 * 128 + tid] + red[4 * 128 + tid] + red[6 * 128 + tid];
        float q = red[1 * 128 + tid] + red[3 * 128 + tid] + red[5 * 128 + tid] + red[7 * 128 + tid];
        part[(size_t)bid * 256 + tid] = s;
        part[(size_t)bid * 256 + 128 + tid] = q;
    }
}

// ---------------------------------------------------------------------------
// gin_s3f body (fused GEMM+aggregation, W LDS tile, zt overlay)
// ---------------------------------------------------------------------------
struct S3fSmem {
    unsigned short wsl[128 * 136];
    float pmv[256];
    int rs[2][33];
    int ci[2][64];
};

__device__ void dev_gin_s3f(S3fSmem* sm, int bid,
                            const unsigned short* __restrict__ uin,
                            const int* __restrict__ row_start,
                            const int* __restrict__ col_idx,
                            const unsigned short* __restrict__ Wt,
                            const float* __restrict__ bias,
                            const float* __restrict__ in_stats, float inv_sM,
                            unsigned short* __restrict__ uout,
                            float* __restrict__ part)
{
    float* zt = (float*)sm->wsl;   // 64*132 floats overlay W tile

    int tid  = threadIdx.x;
    int wave = tid >> 6;
    int lane = tid & 63;
    int quad = lane >> 4;
    int l16  = lane & 15;
    int g0   = bid * 2;
    int row0 = bid * 64;

    if (tid < 128) {
        float s = in_stats[tid], ss = in_stats[128 + tid];
        float mn = s * inv_sM;
        sm->pmv[tid] = mn;
        sm->pmv[128 + tid] = rsqrtf(ss * inv_sM - mn * mn + BN_EPS);
    }
    if (tid < 66) {
        int gl = tid / 33, idx = tid - gl * 33;
        sm->rs[gl][idx] = row_start[(g0 + gl) * 33 + idx];
    }
    if (tid >= 128) {
        int t = tid - 128;
        sm->ci[t >> 6][t & 63] = col_idx[(g0 + (t >> 6)) * EPG + (t & 63)];
    }
    for (int i = tid; i < 128 * 32; i += 256) {
        int n = i >> 5, k = (i & 31) * 4;
        *(us4*)&sm->wsl[n * 136 + k] = *(const us4*)&Wt[(size_t)n * 128 + k];
    }
    __syncthreads();

    bf16x8 afrag[4];
    {
        const unsigned short* ap = uin + (size_t)(row0 + wave * 16 + l16) * 128;
        #pragma unroll
        for (int ks = 0; ks < 4; ++ks) {
            int kb = ks * 32 + quad * 8;
            float v[8];
            bf2f8(*(const bf16x8*)(const void*)&ap[kb], v);
            #pragma unroll
            for (int j = 0; j < 8; ++j)
                v[j] = (fmaxf(v[j], 0.f) - sm->pmv[kb + j]) * sm->pmv[128 + kb + j];
            afrag[ks] = quant8(v);
        }
    }

    f32x4 acc[8];
    #pragma unroll
    for (int j = 0; j < 8; ++j) acc[j] = (f32x4){0.f, 0.f, 0.f, 0.f};
    #pragma unroll
    for (int ks = 0; ks < 4; ++ks) {
        int kb = ks * 32 + quad * 8;
        #pragma unroll
        for (int nt = 0; nt < 8; ++nt) {
            bf16x8 b = *(const bf16x8*)(const void*)&sm->wsl[(nt * 16 + l16) * 136 + kb];
            acc[nt] = __builtin_amdgcn_mfma_f32_16x16x32_bf16(afrag[ks], b, acc[nt], 0, 0, 0);
        }
    }
    __syncthreads();   // ALL waves done reading W -> overlay safe

    #pragma unroll
    for (int nt = 0; nt < 8; ++nt) {
        int col = nt * 16 + l16;
        #pragma unroll
        for (int r = 0; r < 4; ++r)
            zt[(wave * 16 + quad * 4 + r) * 132 + col] = acc[nt][r];
    }
    __syncthreads();

    float sv[4] = {0.f, 0.f, 0.f, 0.f}, qv[4] = {0.f, 0.f, 0.f, 0.f};
    {
        int c4  = (tid & 31) * 4;
        int rg  = tid >> 5;
        int hh  = rg >> 2;
        int rb0 = (rg & 3) * 8;
        float4 bv = *(const float4*)&bias[c4];
        unsigned short* ub = uout + (size_t)row0 * 128;
        for (int rr = 0; rr < 8; ++rr) {
            int r = rb0 + rr;
            int lr = hh * 32 + r;
            float4 val = *(const float4*)&zt[lr * 132 + c4];
            int e0 = sm->rs[hh][r], e1 = sm->rs[hh][r + 1];
            for (int e = e0; e < e1; ++e) {
                float4 zz = *(const float4*)&zt[(hh * 32 + sm->ci[hh][e]) * 132 + c4];
                val.x += zz.x; val.y += zz.y; val.z += zz.z; val.w += zz.w;
            }
            float u0 = val.x + bv.x, u1 = val.y + bv.y;
            float u2 = val.z + bv.z, u3 = val.w + bv.w;
            *(us4*)&ub[(size_t)lr * 128 + c4] =
                (us4){ f2bf(u0), f2bf(u1), f2bf(u2), f2bf(u3) };
            sv[0] += u0; sv[1] += u1; sv[2] += u2; sv[3] += u3;
            qv[0] += u0 * u0; qv[1] += u1 * u1; qv[2] += u2 * u2; qv[3] += u3 * u3;
        }
    }
    __syncthreads();
    {
        int c4 = (tid & 31) * 4, rg = tid >> 5;
        #pragma unroll
        for (int j = 0; j < 4; ++j) {
            zt[rg * 128 + c4 + j] = sv[j];
            zt[1024 + rg * 128 + c4 + j] = qv[j];
        }
    }
    __syncthreads();
    if (tid < 128) {
        float s = 0.f, q = 0.f;
        #pragma unroll
        for (int rg = 0; rg < 8; ++rg) {
            s += zt[rg * 128 + tid];
            q += zt[1024 + rg * 128 + tid];
        }
        part[(size_t)bid * 256 + tid] = s;
        part[(size_t)bid * 256 + 128 + tid] = q;
    }
}

// ---------------------------------------------------------------------------
// gin_lin body (streaming GEMM, W LDS tile)
// ---------------------------------------------------------------------------
struct LinSmem {
    unsigned short Ws_l[128 * 136];
    float pmv[256];
    float red[4][2][128];
};

template<int DO_POOL>
__device__ void dev_gin_lin(LinSmem* sm, int bid,
                            const unsigned short* __restrict__ uin,
                            const unsigned short* __restrict__ Wt,
                            const float* __restrict__ bias,
                            const float* __restrict__ in_stats, float inv_sM,
                            unsigned short* uout,
                            float* __restrict__ part,
                            float* __restrict__ pool_out)
{
    int tid  = threadIdx.x;
    int wave = tid >> 6;
    int lane = tid & 63;
    int quad = lane >> 4;
    int l16  = lane & 15;
    int row0 = bid * 64;

    for (int i = tid; i < 128 * 32; i += 256) {
        int n = i >> 5, k = (i & 31) * 4;
        *(us4*)&sm->Ws_l[n * 136 + k] = *(const us4*)&Wt[(size_t)n * 128 + k];
    }
    if (tid < 128) {
        float s = in_stats[tid], ss = in_stats[128 + tid];
        float mn = s * inv_sM;
        sm->pmv[tid] = mn;
        sm->pmv[128 + tid] = rsqrtf(ss * inv_sM - mn * mn + BN_EPS);
    }
    __syncthreads();

    bf16x8 afrag[4];
    {
        const unsigned short* ap = uin + (size_t)(row0 + wave * 16 + l16) * 128;
        #pragma unroll
        for (int ks = 0; ks < 4; ++ks) {
            int kb = ks * 32 + quad * 8;
            float v[8];
            bf2f8(*(const bf16x8*)(const void*)&ap[kb], v);
            #pragma unroll
            for (int j = 0; j < 8; ++j)
                v[j] = fmaxf((v[j] - sm->pmv[kb + j]) * sm->pmv[128 + kb + j], 0.f);
            afrag[ks] = quant8(v);
        }
    }

    f32x4 acc[8];
    #pragma unroll
    for (int j = 0; j < 8; ++j) acc[j] = (f32x4){0.f, 0.f, 0.f, 0.f};
    #pragma unroll
    for (int ks = 0; ks < 4; ++ks) {
        int kb = ks * 32 + quad * 8;
        #pragma unroll
        for (int nt = 0; nt < 8; ++nt) {
            bf16x8 b = *(const bf16x8*)(const void*)&sm->Ws_l[(nt * 16 + l16) * 136 + kb];
            acc[nt] = __builtin_amdgcn_mfma_f32_16x16x32_bf16(afrag[ks], b, acc[nt], 0, 0, 0);
        }
    }

    float ls[8], lq[8], lm[8];
    #pragma unroll
    for (int nt = 0; nt < 8; ++nt) {
        int col = nt * 16 + l16;
        float bv = bias[col];
        int rb = row0 + wave * 16 + quad * 4;
        float s0 = 0.f, q0 = 0.f, mx = -INFINITY;
        #pragma unroll
        for (int r = 0; r < 4; ++r) {
            float u = acc[nt][r] + bv;
            float ru = fmaxf(u, 0.f);
            s0 += ru; q0 += ru * ru;
            if (DO_POOL) mx = fmaxf(mx, ru);
            else uout[(size_t)(rb + r) * 128 + col] = f2bf(u);
        }
        ls[nt] = s0; lq[nt] = q0; lm[nt] = mx;
    }

    #pragma unroll
    for (int nt = 0; nt < 8; ++nt) {
        float s = ls[nt], q = lq[nt];
        s += __shfl_xor(s, 16); q += __shfl_xor(q, 16);
        s += __shfl_xor(s, 32); q += __shfl_xor(q, 32);
        if (quad == 0) {
            sm->red[wave][0][nt * 16 + l16] = s;
            sm->red[wave][1][nt * 16 + l16] = q;
        }
    }
    __syncthreads();
    if (tid < 128) {
        float s = sm->red[0][0][tid] + sm->red[1][0][tid] + sm->red[2][0][tid] + sm->red[3][0][tid];
        float q = sm->red[0][1][tid] + sm->red[1][1][tid] + sm->red[2][1][tid] + sm->red[3][1][tid];
        part[(size_t)bid * 256 + tid] = s;
        part[(size_t)bid * 256 + 128 + tid] = q;
    }
    if (DO_POOL) {
        __syncthreads();
        #pragma unroll
        for (int nt = 0; nt < 8; ++nt) {
            float m = lm[nt];
            m = fmaxf(m, __shfl_xor(m, 16));
            m = fmaxf(m, __shfl_xor(m, 32));
            if (quad == 0) sm->red[wave][0][nt * 16 + l16] = m;
        }
        __syncthreads();
        {
            int gi = tid >> 7, col = tid & 127;
            float m = fmaxf(sm->red[gi * 2][0][col], sm->red[gi * 2 + 1][0][col]);
            pool_out[(size_t)((row0 >> 5) + gi) * 128 + col] = m;
        }
    }
}

// ---------------------------------------------------------------------------
// gemm_rB body (16-row blocks, W direct from L2)
// ---------------------------------------------------------------------------
struct RBSmem { float pm[256]; float pv[256]; };

template<int KSTEPS, int NT>
__device__ void dev_rB(RBSmem* sm, int bid,
                       const float* __restrict__ A, const float* __restrict__ A2,
                       int lda, int K, int stats_K, int ksplit,
                       const unsigned short* __restrict__ Wt,
                       const float* __restrict__ bias, float* __restrict__ C,
                       const float* __restrict__ in_stats, float inv_sM, int in_mode,
                       float* __restrict__ part, int stats_mode, int out_act)
{
    constexpr int NSUBW = NT / 64;
    int tid  = threadIdx.x;
    int wave = tid >> 6;
    int lane = tid & 63;
    int quad = lane >> 4;
    int l16  = lane & 15;
    int m0   = bid * 16;

    if (in_mode) {
        for (int k = tid; k < KSTEPS * 32; k += 256) {
            float mn = 0.f, iv = 1.f;
            if (k < stats_K) {
                float s = in_stats[k], ss = in_stats[stats_K + k];
                mn = s * inv_sM;
                float vr = ss * inv_sM - mn * mn;
                iv = rsqrtf(vr + BN_EPS);
            }
            sm->pm[k] = mn; sm->pv[k] = iv;
        }
        __syncthreads();
    }

    bf16x8 afrag[KSTEPS];
    {
        int row = m0 + l16;
        const float* ap = A + (size_t)row * lda;
        #pragma unroll
        for (int ks = 0; ks < KSTEPS; ++ks) {
            int kb = ks * 32 + quad * 8;
            float v[8];
            #pragma unroll
            for (int hh = 0; hh < 2; ++hh) {
                int k = kb + hh * 4;
                const float* p = (k >= ksplit) ? &A2[(size_t)row * 128 + (k - 128)]
                                               : &ap[k];
                float4 f = *(const float4*)p;
                v[hh * 4 + 0] = f.x; v[hh * 4 + 1] = f.y;
                v[hh * 4 + 2] = f.z; v[hh * 4 + 3] = f.w;
            }
            if (in_mode) {
                #pragma unroll
                for (int j = 0; j < 8; ++j)
                    v[j] = apply_in(v[j], in_mode, sm->pm[kb + j], sm->pv[kb + j]);
            }
            afrag[ks] = quant8(v);
        }
    }

    f32x4 acc[NSUBW];
    #pragma unroll
    for (int j = 0; j < NSUBW; ++j) acc[j] = (f32x4){0.f, 0.f, 0.f, 0.f};

    #pragma unroll
    for (int ks = 0; ks < KSTEPS; ++ks) {
        #pragma unroll
        for (int nt = 0; nt < NSUBW; ++nt) {
            int wrow = (wave * NSUBW + nt) * 16 + l16;
            bf16x8 b = *(const bf16x8*)(const void*)&Wt[(size_t)wrow * K + ks * 32 + quad * 8];
            acc[nt] = __builtin_amdgcn_mfma_f32_16x16x32_bf16(afrag[ks], b, acc[nt], 0, 0, 0);
        }
    }

    float ls[NSUBW], lq[NSUBW];
    #pragma unroll
    for (int nt = 0; nt < NSUBW; ++nt) { ls[nt] = 0.f; lq[nt] = 0.f; }

    #pragma unroll
    for (int nt = 0; nt < NSUBW; ++nt) {
        int col = (wave * NSUBW + nt) * 16 + l16;
        float bv = bias[col];
        int rbase = m0 + quad * 4;
        #pragma unroll
        for (int r = 0; r < 4; ++r) {
            float u = acc[nt][r] + bv;
            if (C) {
                float wv = out_act ? fmaxf(u, 0.f) : u;
                C[(size_t)(rbase + r) * NT + col] = wv;
            }
            if (stats_mode) {
                float s = (stats_mode == 2) ? fmaxf(u, 0.f) : u;
                ls[nt] += s; lq[nt] += s * s;
            }
        }
    }

    if (stats_mode) {
        #pragma unroll
        for (int nt = 0; nt < NSUBW; ++nt) {
            float s = ls[nt], q = lq[nt];
            s += __shfl_xor(s, 16); q += __shfl_xor(q, 16);
            s += __shfl_xor(s, 32); q += __shfl_xor(q, 32);
            if (quad == 0) {
                int col = (wave * NSUBW + nt) * 16 + l16;
                part[(size_t)bid * 256 + col] = s;
                part[(size_t)bid * 256 + 128 + col] = q;
            }
        }
    }
}

// ---------------------------------------------------------------------------
// gemm_cell body (software-pipelined, K-chunk 128, tile 32 x NT), flattened:
// bid -> m0 = (bid & 255)*32, n-block = bid >> 8.
// ---------------------------------------------------------------------------
template<int NT>
struct CellSmem {
    unsigned short As_l[32 * 136];
    unsigned short Ws_l[NT * 136];
    float red[2][2][NT];
};

template<int NT>
__device__ void dev_gemm_cell(CellSmem<NT>* sm, int bid,
                              const unsigned short* __restrict__ Abf, int abf_str,
                              const unsigned short* __restrict__ Wt,
                              const float* __restrict__ bias, float* __restrict__ C,
                              int K, int N, float* __restrict__ out_stats)
{
    constexpr int NSUB = NT / 32;
    constexpr int WITEMS = NT * 32 / 256;
    int tid = threadIdx.x;
    int wave = tid >> 6;
    int lane = tid & 63;
    int quad = lane >> 4;
    int l16 = lane & 15;
    int mhalf = wave & 1, nhalf = wave >> 1;
    int m0 = (bid & 255) * 32, n0 = (bid >> 8) * NT;

    us8 aReg[2];
    us4 wReg[WITEMS];

    auto loadA = [&](int k0) {
        #pragma unroll
        for (int t = 0; t < 2; ++t) {
            int i = t * 256 + tid;
            int row = i >> 4, c8 = (i & 15) * 8;
            aReg[t] = *(const us8*)&Abf[(size_t)(m0 + row) * abf_str + k0 + c8];
        }
    };
    auto loadW = [&](int k0) {
        #pragma unroll
        for (int t = 0; t < WITEMS; ++t) {
            int i = t * 256 + tid;
            int nn = i >> 5, kt = i & 31;
            int k = k0 + kt * 4;
            int gn = n0 + nn;
            us4 w4 = (us4){0, 0, 0, 0};
            if (gn < N && k < K) w4 = *(const us4*)&Wt[(size_t)gn * K + k];
            wReg[t] = w4;
        }
    };
    auto storeAW = [&]() {
        #pragma unroll
        for (int t = 0; t < 2; ++t) {
            int i = t * 256 + tid;
            int row = i >> 4, c8 = (i & 15) * 8;
            *(us8*)&sm->As_l[row * 136 + c8] = aReg[t];
        }
        #pragma unroll
        for (int t = 0; t < WITEMS; ++t) {
            int i = t * 256 + tid;
            int nn = i >> 5, kt = i & 31;
            *(us4*)&sm->Ws_l[nn * 136 + kt * 4] = wReg[t];
        }
    };

    f32x4 acc[NSUB];
    #pragma unroll
    for (int j = 0; j < NSUB; ++j) acc[j] = (f32x4){0.f, 0.f, 0.f, 0.f};

    int nch = (K + 127) >> 7;
    loadA(0); loadW(0);
    for (int c = 0; c < nch; ++c) {
        storeAW();
        if (c + 1 < nch) { loadA((c + 1) * 128); loadW((c + 1) * 128); }
        __syncthreads();
        #pragma unroll
        for (int ks = 0; ks < 4; ++ks) {
            bf16x8 a = *(const bf16x8*)(const void*)
                &sm->As_l[(mhalf * 16 + l16) * 136 + ks * 32 + quad * 8];
            #pragma unroll
            for (int nt = 0; nt < NSUB; ++nt) {
                bf16x8 b = *(const bf16x8*)(const void*)
                    &sm->Ws_l[(nhalf * (NT / 2) + nt * 16 + l16) * 136 + ks * 32 + quad * 8];
                acc[nt] = __builtin_amdgcn_mfma_f32_16x16x32_bf16(a, b, acc[nt], 0, 0, 0);
            }
        }
        __syncthreads();
    }

    float ls[NSUB], lq[NSUB];
    #pragma unroll
    for (int nt = 0; nt < NSUB; ++nt) { ls[nt] = 0.f; lq[nt] = 0.f; }

    #pragma unroll
    for (int nt = 0; nt < NSUB; ++nt) {
        int col = n0 + nhalf * (NT / 2) + nt * 16 + l16;
        if (col < N) {
            float bv = bias[col];
            int rbase = m0 + mhalf * 16 + quad * 4;
            #pragma unroll
            for (int r = 0; r < 4; ++r) {
                float u = acc[nt][r] + bv;
                C[(size_t)(rbase + r) * N + col] = u;
                ls[nt] += u; lq[nt] += u * u;
            }
        }
    }

    #pragma unroll
    for (int nt = 0; nt < NSUB; ++nt) {
        float s = ls[nt], q = lq[nt];
        s += __shfl_xor(s, 16); q += __shfl_xor(q, 16);
        s += __shfl_xor(s, 32); q += __shfl_xor(q, 32);
        if (quad == 0) {
            int lc = nhalf * (NT / 2) + nt * 16 + l16;
            sm->red[mhalf][0][lc] = s;
            sm->red[mhalf][1][lc] = q;
        }
    }
    __syncthreads();
    if (tid < NT) {
        int col = n0 + tid;
        if (col < N) {
            float s = sm->red[0][0][tid] + sm->red[1][0][tid];
            float q = sm->red[0][1][tid] + sm->red[1][1][tid];
            unsafeAtomicAdd(&out_stats[col], s);
            unsafeAtomicAdd(&out_stats[N + col], q);
        }
    }
}

// ===========================================================================
// Fused kernels (block-range dispatch; LDS = union of branch needs)
// ===========================================================================
__global__ __launch_bounds__(256)
void prep(TransArgs ta, SetupArgs sa, const float* cell, unsigned short* abf,
          int nbT, int nbZC)
{
    __shared__ __align__(16) char smem[sizeof(TransSmem)];
    int b = blockIdx.x;
    if (b < nbT) { dev_transpose((TransSmem*)smem, b, ta); return; }
    b -= nbT;
    if (b < nbZC) { dev_setup((SetupSmem*)smem, b, sa); return; }
    b -= nbZC;
    dev_quant_cell(b, cell, abf);
}

// gin_s1 (slim) + ce1 with NT=64 body: union LDS 27.1 KB (was 45.6 with
// NT=128 -> 3 blocks/CU for BOTH pools; now ~5 blocks/CU).
__global__ __launch_bounds__(256)
void f_s1_ce1(const float* drug_x, const int* row_start, const int* col_idx,
              const unsigned short* W11, const float* b11,
              unsigned short* uout, float* partA,
              const unsigned short* Abf, const unsigned short* Wt0,
              const float* ce1b, float* c1, float* st_c1, int nb1)
{
    constexpr size_t SZ = sizeof(S1Smem) > sizeof(CellSmem<64>)
                        ? sizeof(S1Smem) : sizeof(CellSmem<64>);
    __shared__ __align__(16) char smem[SZ];
    int b = blockIdx.x;
    if (b < nb1)
        dev_gin_s1((S1Smem*)smem, b, drug_x, row_start, col_idx, W11, b11, uout, partA);
    else
        dev_gemm_cell<64>((CellSmem<64>*)smem, b - nb1, Abf, ABF_STR, Wt0,
                          ce1b, c1, CELLD, 516, st_c1);
}

__global__ __launch_bounds__(256)
void f_red_qc1(const float* partA, int nrows, float* out,
               const float* c1, const float* st_c1, float inv_B,
               unsigned short* c1bf, int nb1)
{
    int b = blockIdx.x;
    if (b < nb1) dev_reduce(b, partA, nrows, 128, out);
    else dev_quant_c1(b - nb1, c1, st_c1, inv_B, c1bf);
}

__global__ __launch_bounds__(256)
void f_lin0_ce2(const unsigned short* uin, const unsigned short* Wt4,
                const float* g12b, const float* st_u1, float inv_N,
                unsigned short* uout, float* partA,
                const unsigned short* C1bf, const unsigned short* Wt1,
                const float* ce2b, float* c2, float* st_c2, int nb1)
{
    constexpr size_t SZ = sizeof(LinSmem) > sizeof(CellSmem<64>)
                        ? sizeof(LinSmem) : sizeof(CellSmem<64>);
    __shared__ __align__(16) char smem[SZ];
    int b = blockIdx.x;
    if (b < nb1)
        dev_gin_lin<0>((LinSmem*)smem, b, uin, Wt4, g12b, st_u1, inv_N,
                       uout, partA, nullptr);
    else
        dev_gemm_cell<64>((CellSmem<64>*)smem, b - nb1, C1bf, C1_STR, Wt1,
                          ce2b, c2, 516, 256, st_c2);
}

__global__ __launch_bounds__(256)
void f_red_ce3(const float* partA, int nrows, float* out,
               const float* c2, const unsigned short* Wt2, const float* ce3b,
               float* c3u, const float* st_c2, float inv_B, float* partB, int nb1)
{
    __shared__ __align__(16) char smem[sizeof(RBSmem)];
    int b = blockIdx.x;
    if (b < nb1) dev_reduce(b, partA, nrows, 128, out);
    else dev_rB<8, 128>((RBSmem*)smem, b - nb1, c2, nullptr, 256, 256, 256,
                        1 << 30, Wt2, ce3b, c3u, st_c2, inv_B, 1, partB, 1, 0);
}

__global__ __launch_bounds__(256)
void f_s3f_red(const unsigned short* uin, const int* row_start, const int* col_idx,
               const unsigned short* Wt5, const float* g21b,
               const float* st_u2rel, float inv_N, unsigned short* uout,
               float* partA, const float* partB, int nrowsB, float* st_c3, int nb1)
{
    __shared__ __align__(16) char smem[sizeof(S3fSmem)];
    int b = blockIdx.x;
    if (b < nb1)
        dev_gin_s3f((S3fSmem*)smem, b, uin, row_start, col_idx, Wt5, g21b,
                    st_u2rel, inv_N, uout, partA);
    else
        dev_reduce(b - nb1, partB, nrowsB, 128, st_c3);
}

// ===========================================================================
// Standalone kernels
// ===========================================================================
__global__ __launch_bounds__(256)
void reduce_stats(const float* __restrict__ part, int nrows, int nt,
                  float* __restrict__ out)
{
    dev_reduce(blockIdx.x, part, nrows, nt, out);
}

__global__ __launch_bounds__(256)
void gin_lin1(const unsigned short* uin, const unsigned short* Wt,
              const float* bias, const float* in_stats, float inv_sM,
              float* part, float* pool_out)
{
    __shared__ __align__(16) char smem[sizeof(LinSmem)];
    dev_gin_lin<1>((LinSmem*)smem, blockIdx.x, uin, Wt, bias, in_stats, inv_sM,
                   nullptr, part, pool_out);
}

template<int KSTEPS, int NT>
__global__ __launch_bounds__(256)
void gemm_rB(const float* A, const float* A2, int lda, int K, int stats_K,
             int ksplit, const unsigned short* Wt, const float* bias, float* C,
             const float* in_stats, float inv_sM, int in_mode,
             float* part, int stats_mode, int out_act)
{
    __shared__ __align__(16) char smem[sizeof(RBSmem)];
    dev_rB<KSTEPS, NT>((RBSmem*)smem, blockIdx.x, A, A2, lda, K, stats_K, ksplit,
                       Wt, bias, C, in_stats, inv_sM, in_mode, part, stats_mode, out_act);
}

__global__ void final_dot(const float* __restrict__ u, const float* __restrict__ w,
                          const float* __restrict__ b, float* __restrict__ y,
                          const float* __restrict__ stats, float inv_sM)
{
    __shared__ float pmv[64], piv[64], sw[64];
    int tid = threadIdx.x;
    if (tid < 64) {
        float s = stats[tid], ss = stats[64 + tid];
        float mn = s * inv_sM;
        float vr = ss * inv_sM - mn * mn;
        pmv[tid] = mn;
        piv[tid] = rsqrtf(vr + BN_EPS);
        sw[tid] = w[tid];
    }
    __syncthreads();
    int i = blockIdx.x * blockDim.x + tid;
    if (i >= BGRAPH) return;
    float acc = 0.f;
    #pragma unroll
    for (int k = 0; k < 64; ++k) {
        float v = (u[(size_t)i * 64 + k] - pmv[k]) * piv[k];
        v = (v > 0.f) ? v : expm1f(v);
        acc += v * sw[k];
    }
    y[i] = acc + b[0];
}

// ---------------------------------------------------------------------------
// Host driver. 17 launches; cell chain overlapped with GIN chain via fusion.
// ---------------------------------------------------------------------------
extern "C" void kernel_launch(void* const* d_in, const int* in_sizes, int n_in,
                              void* d_out, int out_size, void* d_ws, size_t ws_size,
                              hipStream_t stream)
{
    const float* cell   = (const float*)d_in[0];
    const float* drug_x = (const float*)d_in[1];
    const int*   eidx   = (const int*)d_in[2];
    const float* ce1w = (const float*)d_in[4];  const float* ce1b = (const float*)d_in[5];
    const float* ce2w = (const float*)d_in[6];  const float* ce2b = (const float*)d_in[7];
    const float* ce3w = (const float*)d_in[8];  const float* ce3b = (const float*)d_in[9];
    const float* g11w = (const float*)d_in[10]; const float* g11b = (const float*)d_in[11];
    const float* g12w = (const float*)d_in[12]; const float* g12b = (const float*)d_in[13];
    const float* g21w = (const float*)d_in[14]; const float* g21b = (const float*)d_in[15];
    const float* g22w = (const float*)d_in[16]; const float* g22b = (const float*)d_in[17];
    const float* d1w  = (const float*)d_in[18]; const float* d1b  = (const float*)d_in[19];
    const float* d2w  = (const float*)d_in[20]; const float* d2b  = (const float*)d_in[21];
    const float* f1w  = (const float*)d_in[22]; const float* f1b  = (const float*)d_in[23];
    const float* f2w  = (const float*)d_in[24]; const float* f2b  = (const float*)d_in[25];
    const float* f3w  = (const float*)d_in[26]; const float* f3b  = (const float*)d_in[27];

    const int* src = eidx;
    const int* dst = eidx + NEDGE;
    float* out = (float*)d_out;

    const float INV_N = 1.f / (float)NNODE;
    const float INV_B = 1.f / (float)BGRAPH;
    const int KBIG = 1 << 30;

    // ---- workspace layout ----
    // ubg (64MB) live through GIN chain; d/head fp32 buffers alias it (dead
    // after lin1). Cell branch OVERLAPS the GIN chain, so c1/c2/c3u get a
    // FRESH region (c2/c3u overlay c1's space only after c1 is dead).
    float* ws = (float*)d_ws;
    unsigned short* ubg = (unsigned short*)ws;            // NNODE*128 ushorts
    float* pbuf = ws + (size_t)NNODE * 64;                // BGRAPH*128 floats
    float* sb   = pbuf + (size_t)BGRAPH * 128;            // 10*1032 stats floats
    unsigned short* wtb = (unsigned short*)(sb + 10 * 1032);
    auto ST = [&](int i) { return sb + (size_t)i * 1032; };
    float* st_u1    = ST(0);
    float* st_u2rel = ST(1);
    float* st_u3    = ST(2);
    float* st_u4rel = ST(3);
    float* st_c1    = ST(4);
    float* st_c2    = ST(5);
    float* st_c3    = ST(6);
    float* st_d1    = ST(7);
    float* st_f1    = ST(8);
    float* st_f2    = ST(9);

    struct WDef { const float* w; int K; int N; };
    WDef wd[11] = {
        {ce1w, CELLD, 516}, {ce2w, 516, 256}, {ce3w, 256, 128},
        {g11w, 9, 128}, {g12w, 128, 128}, {g21w, 128, 128}, {g22w, 128, 128},
        {d1w, 128, 128}, {d2w, 128, 128}, {f1w, 256, 128}, {f2w, 128, 64}
    };
    TransArgs ta;
    int off = 0;
    unsigned short* wt[11];
    ta.off[0] = 0;
    for (int i = 0; i < 11; ++i) {
        wt[i] = wtb + off;
        ta.w[i] = wd[i].w; ta.wt[i] = wt[i];
        ta.K[i] = wd[i].K; ta.N[i] = wd[i].N;
        ta.ntN[i] = (wd[i].N + 63) / 64;
        ta.off[i + 1] = ta.off[i] + ((wd[i].K + 63) / 64) * ta.ntN[i];
        off += wd[i].K * wd[i].N;
    }

    SetupArgs sa;
    sa.zb = sb; sa.zTotal = 10 * 1032; sa.zBlocks = (10 * 1032 + 255) / 256;
    sa.src = src; sa.dst = dst;

    int csr_off = (off + 7) & ~7;
    int* row_start = (int*)(wtb + csr_off);
    int* col_idx   = row_start + (size_t)BGRAPH * 33;
    float* partA = (float*)(col_idx + (size_t)NEDGE);      // 4096*256 floats
    float* partB = partA + (size_t)4096 * 256;             // 512*256 floats
    unsigned short* Abf  = (unsigned short*)(partB + (size_t)512 * 256);
    unsigned short* C1bf = Abf + (size_t)BGRAPH * ABF_STR;
    // fresh fp32 cell region (c1 dead after quant_c1; c2/c3u overlay it)
    float* cellws = (float*)(C1bf + (size_t)BGRAPH * C1_STR);  // 8192*516 floats
    float* c1  = cellws;
    float* c2  = cellws;                                   // written after c1 dead
    float* c3u = cellws + (size_t)BGRAPH * 256;            // disjoint from c2
    // d/head buffers alias ubg (dead by the time these run)
    float* dbuf  = ws;
    float* d2buf = dbuf + (size_t)BGRAPH * 128;
    float* f1o   = d2buf + (size_t)BGRAPH * 128;
    float* f2o   = f1o + (size_t)BGRAPH * 128;
    sa.row_start = row_start; sa.col_idx = col_idx;

    int nbT = ta.off[11];
    int nbZC = sa.zBlocks + BGRAPH / 4;

    // L0: transpose + zero + CSR + quant_cell (all independent)
    prep<<<nbT + nbZC + 8192, 256, 0, stream>>>(ta, sa, cell, Abf, nbT, nbZC);

    // L1: gin_s1 (2048) + ce1 NT=64 (256 m x 9 n = 2304)
    f_s1_ce1<<<2048 + 2304, 256, 0, stream>>>(
        drug_x, row_start, col_idx, wt[3], g11b, ubg, partA,
        Abf, wt[0], ce1b, c1, st_c1, 2048);

    // L2: reduce u1 (64) + quant_c1 (5120)
    f_red_qc1<<<64 + 5120, 256, 0, stream>>>(
        partA, BGRAPH / 4, st_u1, c1, st_c1, INV_B, C1bf, 64);

    // L3: gin_lin<0> (4096) + ce2 (1024)
    f_lin0_ce2<<<4096 + 1024, 256, 0, stream>>>(
        ubg, wt[4], g12b, st_u1, INV_N, ubg, partA,
        C1bf, wt[1], ce2b, c2, st_c2, 4096);

    // L4: reduce u2rel (64) + ce3 (512, writes partB)
    f_red_ce3<<<64 + 512, 256, 0, stream>>>(
        partA, NNODE / 64, st_u2rel, c2, wt[2], ce3b, c3u, st_c2, INV_B, partB, 64);

    // L5: gin_s3f (4096, writes partA) + reduce partB -> st_c3 (64)
    f_s3f_red<<<4096 + 64, 256, 0, stream>>>(
        ubg, row_start, col_idx, wt[5], g21b, st_u2rel, INV_N, ubg, partA,
        partB, BGRAPH / 16, st_c3, 4096);

    reduce_stats<<<64, 256, 0, stream>>>(partA, BGRAPH / 2, 128, st_u3);

    gin_lin1<<<NNODE / 64, 256, 0, stream>>>(
        ubg, wt[6], g22b, st_u3, INV_N, partA, pbuf);
    reduce_stats<<<64, 256, 0, stream>>>(partA, NNODE / 64, 128, st_u4rel);

    // ================= d branch ==============================================
    gemm_rB<4, 128><<<BGRAPH / 16, 256, 0, stream>>>(
        pbuf, nullptr, 128, 128, 128, KBIG, wt[7], d1b, dbuf,
        st_u4rel, INV_N, 3, partA, 1, 0);
    reduce_stats<<<64, 256, 0, stream>>>(partA, BGRAPH / 16, 128, st_d1);
    gemm_rB<4, 128><<<BGRAPH / 16, 256, 0, stream>>>(
        dbuf, nullptr, 128, 128, 128, KBIG, wt[8], d2b, d2buf,
        st_d1, INV_B, 1, partA, 0, 1);

    // ================= head ==================================================
    gemm_rB<8, 128><<<BGRAPH / 16, 256, 0, stream>>>(
        c3u, d2buf, 128, 256, 128, 128, wt[9], f1b, f1o,
        st_c3, INV_B, 1, partA, 1, 0);
    reduce_stats<<<64, 256, 0, stream>>>(partA, BGRAPH / 16, 128, st_f1);
    gemm_rB<4, 64><<<BGRAPH / 16, 256, 0, stream>>>(
        f1o, nullptr, 128, 128, 128, KBIG, wt[10], f2b, f2o,
        st_f1, INV_B, 2, partA, 1, 0);
    reduce_stats<<<64, 256, 0, stream>>>(partA, BGRAPH / 16, 64, st_f2);
    final_dot<<<BGRAPH / 256, 256, 0, stream>>>(f2o, f3w, f3b, out, st_f2, INV_B);
}